// Round 17
// baseline (214.431 us; speedup 1.0000x reference)
//
#include <hip/hip_runtime.h>

#define NB 32
#define ND 128
#define NL 1024
#define NDL (ND*NL)   // 131072 per batch
// stats: 6 regions x 32 batches x 16 floats (one 64B cacheline per (r,b))
#define STATS_B 16
#define STATS_R (32*STATS_B)

typedef __attribute__((ext_vector_type(8))) short bf16x8;
typedef __attribute__((ext_vector_type(4))) float f32x4;
typedef unsigned short u16;

__device__ __forceinline__ f32x4 mfma_bf16_16x16x32(bf16x8 a, bf16x8 b, f32x4 c) {
#if defined(__HIP_DEVICE_COMPILE__)
  return __builtin_amdgcn_mfma_f32_16x16x32_bf16(a, b, c, 0, 0, 0);
#else
  return c;
#endif
}

// HW exp2 via BUILTIN (R8 lesson: raw asm hides TRANS hazard -> NaN)
__device__ __forceinline__ float exp2fast(float x) {
#if defined(__HIP_DEVICE_COMPILE__) && __has_builtin(__builtin_amdgcn_exp2f)
  return __builtin_amdgcn_exp2f(x);
#elif defined(__HIP_DEVICE_COMPILE__)
  return __expf(x * 0.6931471805599453f);
#else
  return x;
#endif
}

// bf16 <-> f32 primitives (R7: avoid library cvt NaN-paths; shift is 1 op)
__device__ __forceinline__ float bf2f(u16 u) {
  union { unsigned u; float f; } c; c.u = ((unsigned)u) << 16; return c.f;
}
__device__ __forceinline__ u16 bf16rnd(float f) {
  union { float f; unsigned u; } c; c.f = f;
  return (u16)((c.u + 0x7FFFu + ((c.u >> 16) & 1u)) >> 16);
}
__device__ __forceinline__ unsigned packpair(float a, float b) {
  return (unsigned)bf16rnd(a) | ((unsigned)bf16rnd(b) << 16);
}
// 3-op truncating pack for attention P (R9: trunc bias ~0.2%, headroom allows)
__device__ __forceinline__ unsigned packtrunc(float a, float b) {
  unsigned ua = __float_as_uint(a), ub = __float_as_uint(b);
  return (ub & 0xFFFF0000u) | (ua >> 16);
}
__device__ __forceinline__ bf16x8 packbf8(float4 a, float4 b) {
  union { unsigned u[4]; bf16x8 v; } r;
  r.u[0] = packpair(a.x, a.y); r.u[1] = packpair(a.z, a.w);
  r.u[2] = packpair(b.x, b.y); r.u[3] = packpair(b.z, b.w);
  return r.v;
}

// Block-level sum/sumsq reduction -> ONE atomic pair per block (R4 lesson)
__device__ __forceinline__ void blockRedAtomic(float s, float sq, float* base) {
  __shared__ float red[32];
#pragma unroll
  for (int off = 32; off > 0; off >>= 1) {
    s  += __shfl_down(s, off, 64);
    sq += __shfl_down(sq, off, 64);
  }
  int wave = threadIdx.x >> 6;
  int nw = blockDim.x >> 6;
  if ((threadIdx.x & 63) == 0) { red[wave*2] = s; red[wave*2+1] = sq; }
  __syncthreads();
  if (threadIdx.x == 0) {
    float ts = 0.f, tq = 0.f;
    for (int i = 0; i < nw; ++i) { ts += red[i*2]; tq += red[i*2+1]; }
    unsafeAtomicAdd(base,     ts);
    unsafeAtomicAdd(base + 1, tq);
  }
}

__global__ void k_zero(float* stats) {
  int t = threadIdx.x;
#pragma unroll
  for (int i = 0; i < 3; ++i) stats[i*1024 + t] = 0.f;
}

// ---------------- per-batch mask length (once, not per attn block) ----------
__global__ __launch_bounds__(256) void k_len(const float* __restrict__ mask,
                                             int* __restrict__ lenbuf) {
  __shared__ int csh;
  int b = blockIdx.x, tid = threadIdx.x;
  if (tid == 0) csh = 0;
  __syncthreads();
  int cnt = 0;
  for (int i = tid; i < NL; i += 256) cnt += (mask[(size_t)b*NL + i] == 0.f) ? 1 : 0;
#pragma unroll
  for (int off = 32; off > 0; off >>= 1) cnt += __shfl_down(cnt, off, 64);
  if ((tid & 63) == 0) atomicAdd(&csh, cnt);
  __syncthreads();
  if (tid == 0) lenbuf[b] = csh;
}

// ---------------- res16 = bf16(x + pos_enc); stats region 0 ----------
__global__ __launch_bounds__(256) void k_addpos(const float* __restrict__ x,
                                                const float* __restrict__ pe,
                                                u16* __restrict__ res,
                                                float* __restrict__ stats0) {
  int b = blockIdx.x >> 6;
  int off = ((blockIdx.x & 63) << 11) + (threadIdx.x << 3);
  const float4* xp = (const float4*)(x + (size_t)b*NDL + off);
  const float4* pp = (const float4*)(pe + off);
  float s = 0.f, sq = 0.f;
  float rv[8];
#pragma unroll
  for (int i = 0; i < 2; ++i) {
    float4 a = xp[i], p = pp[i];
    rv[i*4+0] = a.x + p.x; rv[i*4+1] = a.y + p.y;
    rv[i*4+2] = a.z + p.z; rv[i*4+3] = a.w + p.w;
  }
#pragma unroll
  for (int j = 0; j < 8; ++j) { s += rv[j]; sq += rv[j]*rv[j]; }
  uint4 pk;
  pk.x = packpair(rv[0], rv[1]); pk.y = packpair(rv[2], rv[3]);
  pk.z = packpair(rv[4], rv[5]); pk.w = packpair(rv[6], rv[7]);
  *(uint4*)(res + (size_t)b*NDL + off) = pk;
  blockRedAtomic(s, sq, stats0 + b*STATS_B);
}

// ============ MFMA GEMM (64-l tile, 1024 thr / 16 waves, l-split) ============
// R16: grid 512 x 512thr = 16 waves/CU (50%) was the GEMM limiter. 16 waves
// split the TILE: wave = (row-strip wave&7, l-half wave>>3) — disjoint outputs,
// no LDS partials/syncs (R11) and no W-traffic growth (R12). 2 blocks/CU x 16
// waves = 32 waves/CU IF VGPR<=64 — hence NO min-waves force (R15: forcing it
// spilled to scratch, VGPR 32, 2x slower). acc[2]+af[4] keeps natural VGPR low.
// xs layout (u32 = 2 bf16 along c): xs[(l<<6) | (c2 ^ ((l&7)<<2))];
// frag read byte off = (l*256 + kk*64 + hi*16) ^ ((lo&7)<<4) (conflict-free).

__device__ __forceinline__ void load_w_frags16(const float* __restrict__ W,
                                               int wo, int lo, int hi, bf16x8 af[4]) {
#pragma unroll
  for (int kk = 0; kk < 4; ++kk) {
    const float4* wp = (const float4*)(W + (size_t)(wo + lo)*128 + kk*32 + hi*8);
    af[kk] = packbf8(wp[0], wp[1]);
  }
}

__device__ __forceinline__ void mfma_core2(const unsigned* xs, bf16x8 af[4],
                                           int lo, int hi, int loff, f32x4 acc[2]) {
#pragma unroll
  for (int ln = 0; ln < 2; ++ln) {
#pragma unroll
    for (int kk = 0; kk < 4; ++kk) {
      int l = loff + ln*16 + lo;
      int off = (l*256 + kk*64 + hi*16) ^ ((lo & 7) << 4);
      bf16x8 bf = *(const bf16x8*)((const char*)xs + off);
      acc[ln] = mfma_bf16_16x16x32(af[kk], bf, acc[ln]);
    }
  }
}

// LN + depthwise-7 conv, bf16 source row, 4 outputs starting at `base`.
__device__ __forceinline__ void conv_row4(const u16* __restrict__ srow,
                                          const float* __restrict__ lwrow,
                                          const float* __restrict__ lbrow,
                                          int base, float mu, float rstd,
                                          const float* wk, float bias0,
                                          float* h /*[4]*/) {
  float wa[10];
  bool interior = (base >= 4) && (base + 8 <= NL);
  if (interior) {
    const uint2* sp = (const uint2*)(srow + base - 4);
    const float4* wp = (const float4*)(lwrow + base - 4);
    const float4* bp = (const float4*)(lbrow + base - 4);
#pragma unroll
    for (int qd = 0; qd < 3; ++qd) {
      uint2 sv2 = sp[qd];
      float4 w4 = wp[qd], b4 = bp[qd];
      float sv[4] = {bf2f((u16)(sv2.x & 0xFFFF)), bf2f((u16)(sv2.x >> 16)),
                     bf2f((u16)(sv2.y & 0xFFFF)), bf2f((u16)(sv2.y >> 16))};
      float wv[4] = {w4.x, w4.y, w4.z, w4.w};
      float bv[4] = {b4.x, b4.y, b4.z, b4.w};
#pragma unroll
      for (int e = 0; e < 4; ++e) {
        int j = qd*4 + e - 1;
        if (j >= 0 && j < 10)
          wa[j] = (sv[e] - mu)*rstd*wv[e] + bv[e];
      }
    }
  } else {
#pragma unroll
    for (int j = 0; j < 10; ++j) {
      int gl = base + j - 3;
      float v = 0.f;
      if (gl >= 0 && gl < NL)
        v = (bf2f(srow[gl]) - mu)*rstd*lwrow[gl] + lbrow[gl];
      wa[j] = v;
    }
  }
#pragma unroll
  for (int l = 0; l < 4; ++l) {
    float acc = bias0;
#pragma unroll
    for (int j = 0; j < 7; ++j) acc += wa[l+j]*wk[j];
    h[l] = acc;
  }
}

// MODE 0: wr16 = bf16(relu(W @ dwconv(LN(src16)) + bias) + res16)  (+stats)
// MODE 1: wr16 = bf16((W@src16 + bias) + res16)                     (+stats)
// MODE 3: outf = relu(W@LN(src16) + bias) + res16                   (f32 out)
template<int MODE>
__global__ __launch_bounds__(1024) void k_gemm_mfma(
    const u16* __restrict__ src16, const float* __restrict__ W,
    const float* __restrict__ bias,
    const u16* __restrict__ res16, u16* __restrict__ wr16,
    float* __restrict__ outf,
    const float* __restrict__ lnw, const float* __restrict__ lnb,
    const float* __restrict__ dww, const float* __restrict__ dwb,
    const float* __restrict__ statsIn, float* __restrict__ statsOut) {
  __shared__ unsigned xs[4096];   // 16 KB: 64 l x 128 c bf16
  int b  = blockIdx.x >> 4;
  int l0 = (blockIdx.x & 15) << 6;
  int tid = threadIdx.x;
  int wave = tid >> 6, lane = tid & 63;
  int lo = lane & 15, hi = lane >> 4;
  int wo = (wave & 7) * 16;     // row strip
  int loff = (wave >> 3) * 32;  // l half

  float mu = 0.f, rstd = 0.f;
  if (MODE == 0 || MODE == 3) {
    mu = statsIn[b*STATS_B] * (1.f/NDL);
    rstd = rsqrtf(statsIn[b*STATS_B + 1]*(1.f/NDL) - mu*mu + 1e-5f);
  }

  // staging: 1024 threads, each one c-pair x 4-l quad
  int c2 = tid >> 4, lq4 = (tid & 15) << 2;
  int c = c2*2;
  if (MODE == 0) {
    int base = l0 + lq4;
    float wk0[7], wk1[7];
#pragma unroll
    for (int j = 0; j < 7; ++j) { wk0[j] = dww[c*7 + j]; wk1[j] = dww[(c+1)*7 + j]; }
    const u16* sa = src16 + (size_t)b*NDL + (size_t)c*NL;
    const float* la  = lnw + (size_t)c*NL;
    const float* lbv = lnb + (size_t)c*NL;
    float h0[4], h1[4];
    conv_row4(sa,      la,      lbv,      base, mu, rstd, wk0, dwb[c],   h0);
    conv_row4(sa + NL, la + NL, lbv + NL, base, mu, rstd, wk1, dwb[c+1], h1);
#pragma unroll
    for (int l = 0; l < 4; ++l) {
      int ll = lq4 + l;
      xs[(ll << 6) | (c2 ^ ((ll & 7) << 2))] = packpair(h0[l], h1[l]);
    }
  } else if (MODE == 1) {
    const u16* sp = src16 + (size_t)b*NDL + (size_t)c*NL + l0 + lq4;
    uint2 ra = *(const uint2*)sp;
    uint2 rb = *(const uint2*)(sp + NL);
    unsigned wv[4];
    wv[0] = (ra.x & 0xFFFFu) | (rb.x << 16);
    wv[1] = (ra.x >> 16)     | (rb.x & 0xFFFF0000u);
    wv[2] = (ra.y & 0xFFFFu) | (rb.y << 16);
    wv[3] = (ra.y >> 16)     | (rb.y & 0xFFFF0000u);
#pragma unroll
    for (int j = 0; j < 4; ++j) {
      int l = lq4 + j;
      xs[(l << 6) | (c2 ^ ((l & 7) << 2))] = wv[j];
    }
  } else {
    const u16* sp = src16 + (size_t)b*NDL + (size_t)c*NL + l0 + lq4;
    uint2 ra = *(const uint2*)sp;
    uint2 rb = *(const uint2*)(sp + NL);
    float sa[4] = {bf2f((u16)(ra.x & 0xFFFF)), bf2f((u16)(ra.x >> 16)),
                   bf2f((u16)(ra.y & 0xFFFF)), bf2f((u16)(ra.y >> 16))};
    float sb[4] = {bf2f((u16)(rb.x & 0xFFFF)), bf2f((u16)(rb.x >> 16)),
                   bf2f((u16)(rb.y & 0xFFFF)), bf2f((u16)(rb.y >> 16))};
    size_t gi = (size_t)c*NL + l0 + lq4;
    float4 w0 = *(const float4*)(lnw + gi), w1 = *(const float4*)(lnw + gi + NL);
    float4 bb0 = *(const float4*)(lnb + gi), bb1 = *(const float4*)(lnb + gi + NL);
    float va[4] = {(sa[0]-mu)*rstd*w0.x + bb0.x, (sa[1]-mu)*rstd*w0.y + bb0.y,
                   (sa[2]-mu)*rstd*w0.z + bb0.z, (sa[3]-mu)*rstd*w0.w + bb0.w};
    float vb[4] = {(sb[0]-mu)*rstd*w1.x + bb1.x, (sb[1]-mu)*rstd*w1.y + bb1.y,
                   (sb[2]-mu)*rstd*w1.z + bb1.z, (sb[3]-mu)*rstd*w1.w + bb1.w};
#pragma unroll
    for (int j = 0; j < 4; ++j) {
      int l = lq4 + j;
      xs[(l << 6) | (c2 ^ ((l & 7) << 2))] = packpair(va[j], vb[j]);
    }
  }

  // prefetch residual (R13: hide epilogue HBM latency under staging+MFMA)
  u16 rpre[8];
#pragma unroll
  for (int ln = 0; ln < 2; ++ln)
#pragma unroll
    for (int r = 0; r < 4; ++r)
      rpre[ln*4+r] = res16[((size_t)b*ND + wo + hi*4 + r)*NL + l0 + loff + ln*16 + lo];

  bf16x8 af[4];
  load_w_frags16(W, wo, lo, hi, af);
  f32x4 acc[2];
#pragma unroll
  for (int ln = 0; ln < 2; ++ln) acc[ln] = (f32x4){0.f,0.f,0.f,0.f};

  __syncthreads();
  mfma_core2(xs, af, lo, hi, loff, acc);

  if (MODE == 0 || MODE == 1) {
    float s = 0.f, sq = 0.f;
#pragma unroll
    for (int ln = 0; ln < 2; ++ln) {
      int l = l0 + loff + ln*16 + lo;
#pragma unroll
      for (int r = 0; r < 4; ++r) {
        int o = wo + hi*4 + r;
        size_t gi = ((size_t)b*ND + o)*NL + l;
        float v = acc[ln][r] + bias[o];
        if (MODE == 0) v = fmaxf(v, 0.f);
        v += bf2f(rpre[ln*4+r]);
        wr16[gi] = bf16rnd(v);
        s += v; sq += v*v;
      }
    }
    blockRedAtomic(s, sq, statsOut + b*STATS_B);
  } else {
#pragma unroll
    for (int ln = 0; ln < 2; ++ln) {
      int l = l0 + loff + ln*16 + lo;
#pragma unroll
      for (int r = 0; r < 4; ++r) {
        int o = wo + hi*4 + r;
        size_t gi = ((size_t)b*ND + o)*NL + l;
        outf[gi] = fmaxf(acc[ln][r] + bias[o], 0.f) + bf2f(rpre[ln*4+r]);
      }
    }
  }
}

// Fused QKV (1024 thr, l-split, no min-waves force): LN staged once, 3 GEMMs.
// q scaled by 0.25*log2e so attention uses raw HW exp2.
__global__ __launch_bounds__(1024) void k_qkv_mfma(
    const u16* __restrict__ src16,
    const float* __restrict__ qw, const float* __restrict__ kw, const float* __restrict__ vw,
    const float* __restrict__ qb, const float* __restrict__ kb, const float* __restrict__ vb,
    u16* __restrict__ qo, u16* __restrict__ ko, u16* __restrict__ vo,
    const float* __restrict__ lnw, const float* __restrict__ lnb,
    const float* __restrict__ statsIn) {
  __shared__ unsigned xs[4096];
  int b  = blockIdx.x >> 4;
  int l0 = (blockIdx.x & 15) << 6;
  int tid = threadIdx.x;
  int wave = tid >> 6, lane = tid & 63;
  int lo = lane & 15, hi = lane >> 4;
  int wo = (wave & 7) * 16;
  int loff = (wave >> 3) * 32;

  float mu = statsIn[b*STATS_B] * (1.f/NDL);
  float rstd = rsqrtf(statsIn[b*STATS_B + 1]*(1.f/NDL) - mu*mu + 1e-5f);
  {
    int c2 = tid >> 4, lq4 = (tid & 15) << 2;
    int c = c2*2;
    const u16* sp = src16 + (size_t)b*NDL + (size_t)c*NL + l0 + lq4;
    uint2 ra = *(const uint2*)sp;
    uint2 rb = *(const uint2*)(sp + NL);
    float sa[4] = {bf2f((u16)(ra.x & 0xFFFF)), bf2f((u16)(ra.x >> 16)),
                   bf2f((u16)(ra.y & 0xFFFF)), bf2f((u16)(ra.y >> 16))};
    float sb[4] = {bf2f((u16)(rb.x & 0xFFFF)), bf2f((u16)(rb.x >> 16)),
                   bf2f((u16)(rb.y & 0xFFFF)), bf2f((u16)(rb.y >> 16))};
    size_t gi = (size_t)c*NL + l0 + lq4;
    float4 w0 = *(const float4*)(lnw + gi), w1 = *(const float4*)(lnw + gi + NL);
    float4 bb0 = *(const float4*)(lnb + gi), bb1 = *(const float4*)(lnb + gi + NL);
    float va[4] = {(sa[0]-mu)*rstd*w0.x + bb0.x, (sa[1]-mu)*rstd*w0.y + bb0.y,
                   (sa[2]-mu)*rstd*w0.z + bb0.z, (sa[3]-mu)*rstd*w0.w + bb0.w};
    float vb4[4] = {(sb[0]-mu)*rstd*w1.x + bb1.x, (sb[1]-mu)*rstd*w1.y + bb1.y,
                    (sb[2]-mu)*rstd*w1.z + bb1.z, (sb[3]-mu)*rstd*w1.w + bb1.w};
#pragma unroll
    for (int j = 0; j < 4; ++j) {
      int l = lq4 + j;
      xs[(l << 6) | (c2 ^ ((l & 7) << 2))] = packpair(va[j], vb4[j]);
    }
  }
  __syncthreads();

  const float* Ws[3] = {qw, kw, vw};
  const float* Bs[3] = {qb, kb, vb};
  u16* Os[3] = {qo, ko, vo};
#pragma unroll 1
  for (int mat = 0; mat < 3; ++mat) {
    bf16x8 af[4];
    load_w_frags16(Ws[mat], wo, lo, hi, af);
    f32x4 acc[2];
#pragma unroll
    for (int ln = 0; ln < 2; ++ln) acc[ln] = (f32x4){0.f,0.f,0.f,0.f};
    mfma_core2(xs, af, lo, hi, loff, acc);
    float oscale = (mat == 0) ? 0.25f*1.4426950408889634f : 1.0f;
    const float* bias = Bs[mat];
    u16* op = Os[mat];
#pragma unroll
    for (int ln = 0; ln < 2; ++ln) {
      int l = l0 + loff + ln*16 + lo;
      int o4 = wo + hi*4;
      float vx = (acc[ln][0] + bias[o4+0]) * oscale;
      float vy = (acc[ln][1] + bias[o4+1]) * oscale;
      float vz = (acc[ln][2] + bias[o4+2]) * oscale;
      float vw4 = (acc[ln][3] + bias[o4+3]) * oscale;
      uint2 pk; pk.x = packpair(vx, vy); pk.y = packpair(vz, vw4);
      *(uint2*)(op + ((size_t)b*NL + l)*ND + o4) = pk;
    }
  }
}

// ---------------- fused MFMA attention (quarter-split, V-only LDS) ------------
// R16 config, unchanged: 2048 blocks x 512 thr, natural VGPR 40, Occ 41%.
template<bool MASKED>
__device__ __forceinline__ void attn_tile(bf16x8 kf0, bf16x8 kf1, bf16x8 vf,
                                          bf16x8 onesf, const bf16x8 qf[2],
                                          f32x4 acc[2], f32x4 dacc[2],
                                          int kb, int len, int hi) {
#pragma unroll
  for (int qt = 0; qt < 2; ++qt) {
    f32x4 z = (f32x4){0.f,0.f,0.f,0.f};
    f32x4 s0 = mfma_bf16_16x16x32(kf0, qf[qt], z);
    f32x4 s1 = mfma_bf16_16x16x32(kf1, qf[qt], z);
    float e[8];
#pragma unroll
    for (int r = 0; r < 4; ++r) {
      float e0 = exp2fast(s0[r]);
      float e1 = exp2fast(s1[r]);
      if (MASKED) {
        e0 = (kb + hi*4 + r < len)      ? e0 : 0.f;
        e1 = (kb + 16 + hi*4 + r < len) ? e1 : 0.f;
      }
      e[r] = e0; e[r+4] = e1;
    }
    union { unsigned u[4]; bf16x8 v; } pu;
    pu.u[0] = packtrunc(e[0], e[1]);
    pu.u[1] = packtrunc(e[2], e[3]);
    pu.u[2] = packtrunc(e[4], e[5]);
    pu.u[3] = packtrunc(e[6], e[7]);
    acc[qt]  = mfma_bf16_16x16x32(vf,    pu.v, acc[qt]);
    dacc[qt] = mfma_bf16_16x16x32(onesf, pu.v, dacc[qt]);
  }
}

__device__ __forceinline__ bf16x8 ldKrow(const u16* kbase, int key, int hi) {
  union { uint4 u; bf16x8 v; } r;
  r.u = *(const uint4*)(kbase + (size_t)key*ND + hi*8);
  return r.v;
}

__global__ __launch_bounds__(512) void k_attn_fused(
    const u16* __restrict__ q, const u16* __restrict__ k,
    const u16* __restrict__ v, const int* __restrict__ lenbuf,
    u16* __restrict__ att_t) {
  __shared__ short kv[16384];   // 32 KB: V fragments only
  int bid = blockIdx.x;
  int b  = bid >> 5;
  int h  = (bid >> 2) & 7;
  int qq = bid & 3;
  int tid = threadIdx.x;
  int len = lenbuf[b];
  int nkt = (len + 31) >> 5;
  int kstage = nkt << 5;

  // ---- stage V: (key-pair, d-quad) tasks; interleave two key rows
  for (int idx = tid; idx < 2048; idx += 512) {
    int keyp = idx >> 2, vq = idx & 3;
    int key = keyp*2;
    if (key >= kstage) break;
    int vlo = vq*4;
    uint2 ra, rb; ra.x = ra.y = rb.x = rb.y = 0u;
    size_t voff = ((size_t)b*NL + key)*ND + h*16 + vlo;
    if (key < len)     ra = *(const uint2*)(v + voff);
    if (key + 1 < len) rb = *(const uint2*)(v + voff + ND);
    unsigned wv[4];
    wv[0] = (ra.x & 0xFFFFu) | (rb.x << 16);
    wv[1] = (ra.x >> 16)     | (rb.x & 0xFFFF0000u);
    wv[2] = (ra.y & 0xFFFFu) | (rb.y << 16);
    wv[3] = (ra.y >> 16)     | (rb.y & 0xFFFF0000u);
    int kt = key >> 5, w = key & 31;  // even
    int vhi, ii;
    if (w < 16) { vhi = w >> 2; ii = w & 3; }
    else        { vhi = (w - 16) >> 2; ii = 4 + (w & 3); }
#pragma unroll
    for (int e = 0; e < 4; ++e)
      *(unsigned*)(kv + kt*512 + (vhi*16 + vlo + e)*8 + ii) = wv[e];
  }
  __syncthreads();

  int wave = tid >> 6, lane = tid & 63;
  int lo = lane & 15, hi = lane >> 4;
  int q0 = qq*256 + wave*32;

  bf16x8 qf[2];
#pragma unroll
  for (int qt = 0; qt < 2; ++qt) {
    if (hi < 2) {
      union { uint4 u; bf16x8 v; } qu;
      qu.u = *(const uint4*)(q + ((size_t)b*NL + q0 + qt*16 + lo)*ND + h*16 + hi*8);
      qf[qt] = qu.v;
    } else {
      qf[qt] = (bf16x8){0,0,0,0,0,0,0,0};
    }
  }
  const short oneb = (short)0x3F80;   // bf16 1.0
  bf16x8 onesf = (bf16x8){oneb,oneb,oneb,oneb,oneb,oneb,oneb,oneb};
  f32x4 acc[2], dacc[2];
#pragma unroll
  for (int qt = 0; qt < 2; ++qt) {
    acc[qt]  = (f32x4){0.f,0.f,0.f,0.f};
    dacc[qt] = (f32x4){0.f,0.f,0.f,0.f};
  }

  int fullt = len >> 5;
  const u16* kbase = k + (size_t)b*NL*ND + h*16;

  // register double-buffer: K direct from global (L2), V from LDS
  bf16x8 cka = (bf16x8){0,0,0,0,0,0,0,0}, ckb = cka, cv;
  if (hi < 2) {
    cka = ldKrow(kbase, lo, hi);
    ckb = ldKrow(kbase, 16 + lo, hi);
  }
  cv = *(const bf16x8*)(kv + lane*8);

  for (int kt = 0; kt < nkt; ++kt) {
    bf16x8 nka = cka, nkb = ckb, nv = cv;
    if (kt + 1 < nkt) {
      int kb2 = (kt+1)*32;
      if (hi < 2) {
        nka = ldKrow(kbase, kb2 + lo, hi);
        nkb = ldKrow(kbase, kb2 + 16 + lo, hi);
      }
      nv = *(const bf16x8*)(kv + (kt+1)*512 + lane*8);
    }
    if (kt < fullt) attn_tile<false>(cka, ckb, cv, onesf, qf, acc, dacc, kt*32, len, hi);
    else            attn_tile<true >(cka, ckb, cv, onesf, qf, acc, dacc, kt*32, len, hi);
    cka = nka; ckb = nkb; cv = nv;
  }
#pragma unroll
  for (int qt = 0; qt < 2; ++qt) {
    float inv = 1.f / dacc[qt][0];   // every C-row of ones-MFMA = full row-sum
    size_t obase = ((size_t)b*ND + h*16)*NL + q0 + qt*16 + lo;
#pragma unroll
    for (int r = 0; r < 4; ++r)
      att_t[obase + (size_t)(hi*4 + r)*NL] = bf16rnd(acc[qt][r] * inv);
  }
}

// ---------------- launcher ----------------
extern "C" void kernel_launch(void* const* d_in, const int* in_sizes, int n_in,
                              void* d_out, int out_size, void* d_ws, size_t ws_size,
                              hipStream_t stream) {
  (void)in_sizes; (void)n_in; (void)out_size; (void)ws_size;
  const float* x       = (const float*)d_in[0];
  const float* mask    = (const float*)d_in[1];
  const float* pe      = (const float*)d_in[2];
  const float* normb_w = (const float*)d_in[3];
  const float* normb_b = (const float*)d_in[4];
  const float* dw_w    = (const float*)d_in[5];
  const float* dw_b    = (const float*)d_in[6];
  const float* pw_w    = (const float*)d_in[7];
  const float* pw_b    = (const float*)d_in[8];
  const float* norms_w = (const float*)d_in[9];
  const float* norms_b = (const float*)d_in[10];
  const float* qw      = (const float*)d_in[11];
  const float* qb      = (const float*)d_in[12];
  const float* kw      = (const float*)d_in[13];
  const float* kb      = (const float*)d_in[14];
  const float* vw      = (const float*)d_in[15];
  const float* vb      = (const float*)d_in[16];
  const float* aw      = (const float*)d_in[17];
  const float* ab      = (const float*)d_in[18];
  const float* norme_w = (const float*)d_in[19];
  const float* norme_b = (const float*)d_in[20];
  const float* fw      = (const float*)d_in[21];
  const float* fb      = (const float*)d_in[22];

  float* out = (float*)d_out;
  float* ws  = (float*)d_ws;
  const size_t NT = (size_t)NB*ND*NL;   // element count per (B,D,L) tensor
  u16* resA = (u16*)ws;                  // NT bf16 = NT/2 floats
  u16* resB = (u16*)(ws + NT/2);
  u16* qb16 = (u16*)(ws + NT);
  u16* kb16 = (u16*)(ws + 3*NT/2);
  u16* vb16 = (u16*)(ws + 2*NT);
  float* stats = ws + 3*NT;              // 6 * STATS_R floats
  int* lenbuf = (int*)(stats + 6*STATS_R);
  u16* att16 = resB;                     // resB free after conv chain

  k_zero<<<dim3(1), dim3(1024), 0, stream>>>(stats);
  k_len<<<dim3(NB), dim3(256), 0, stream>>>(mask, lenbuf);
  k_addpos<<<dim3(2048), dim3(256), 0, stream>>>(x, pe, resA, stats);

  // conv layers ping-pong A->B->A->B->A (halo reads never race with writes)
  for (int i = 0; i < 4; ++i) {
    const float* lw = (i == 0) ? normb_w : norms_w + (size_t)(i-1)*NDL;
    const float* lb = (i == 0) ? normb_b : norms_b + (size_t)(i-1)*NDL;
    const u16* rsrc = (i & 1) ? resB : resA;
    u16*       rdst = (i & 1) ? resA : resB;
    k_gemm_mfma<0><<<dim3(NB*16), dim3(1024), 0, stream>>>(
        rsrc, pw_w + i*ND*ND, pw_b + i*ND, rsrc, rdst, nullptr,
        lw, lb, dw_w + i*ND*7, dw_b + i*ND,
        stats + i*STATS_R, stats + (i+1)*STATS_R);
  }
  // after 4 layers res lives in resA

  const float* ln3w = norms_w + (size_t)3*NDL;
  const float* ln3b = norms_b + (size_t)3*NDL;
  k_qkv_mfma<<<dim3(NB*16), dim3(1024), 0, stream>>>(
      resA, qw, kw, vw, qb, kb, vb, qb16, kb16, vb16, ln3w, ln3b, stats + 4*STATS_R);

  k_attn_fused<<<dim3(NB*8*4), dim3(512), 0, stream>>>(qb16, kb16, vb16, lenbuf, att16);

  // attn out proj: bf16 src, residual resA, in-place (no halo -> safe)
  k_gemm_mfma<1><<<dim3(NB*16), dim3(1024), 0, stream>>>(
      att16, aw, ab, resA, resA, nullptr, nullptr, nullptr, nullptr, nullptr,
      nullptr, stats + 5*STATS_R);
  k_gemm_mfma<3><<<dim3(NB*16), dim3(1024), 0, stream>>>(
      resA, fw, fb, resA, nullptr, out, norme_w, norme_b, nullptr, nullptr,
      stats + 5*STATS_R, nullptr);
}

// Round 18
// 167.521 us; speedup vs baseline: 1.2800x; 1.2800x over previous
//
#include <hip/hip_runtime.h>

#define NB 32
#define ND 128
#define NL 1024
#define NDL (ND*NL)   // 131072 per batch
// stats: 6 regions x 32 batches x 16 floats (one 64B cacheline per (r,b))
#define STATS_B 16
#define STATS_R (32*STATS_B)

typedef __attribute__((ext_vector_type(8))) short bf16x8;
typedef __attribute__((ext_vector_type(4))) float f32x4;
typedef unsigned short u16;

__device__ __forceinline__ f32x4 mfma_bf16_16x16x32(bf16x8 a, bf16x8 b, f32x4 c) {
#if defined(__HIP_DEVICE_COMPILE__)
  return __builtin_amdgcn_mfma_f32_16x16x32_bf16(a, b, c, 0, 0, 0);
#else
  return c;
#endif
}

// HW exp2 via BUILTIN (R8 lesson: raw asm hides TRANS hazard -> NaN)
__device__ __forceinline__ float exp2fast(float x) {
#if defined(__HIP_DEVICE_COMPILE__) && __has_builtin(__builtin_amdgcn_exp2f)
  return __builtin_amdgcn_exp2f(x);
#elif defined(__HIP_DEVICE_COMPILE__)
  return __expf(x * 0.6931471805599453f);
#else
  return x;
#endif
}

// bf16 <-> f32 primitives (R7: avoid library cvt NaN-paths; shift is 1 op)
__device__ __forceinline__ float bf2f(u16 u) {
  union { unsigned u; float f; } c; c.u = ((unsigned)u) << 16; return c.f;
}
__device__ __forceinline__ u16 bf16rnd(float f) {
  union { float f; unsigned u; } c; c.f = f;
  return (u16)((c.u + 0x7FFFu + ((c.u >> 16) & 1u)) >> 16);
}
__device__ __forceinline__ unsigned packpair(float a, float b) {
  return (unsigned)bf16rnd(a) | ((unsigned)bf16rnd(b) << 16);
}
// 3-op truncating pack for attention P (R9: trunc bias ~0.2%, headroom allows)
__device__ __forceinline__ unsigned packtrunc(float a, float b) {
  unsigned ua = __float_as_uint(a), ub = __float_as_uint(b);
  return (ub & 0xFFFF0000u) | (ua >> 16);
}
__device__ __forceinline__ bf16x8 packbf8(float4 a, float4 b) {
  union { unsigned u[4]; bf16x8 v; } r;
  r.u[0] = packpair(a.x, a.y); r.u[1] = packpair(a.z, a.w);
  r.u[2] = packpair(b.x, b.y); r.u[3] = packpair(b.z, b.w);
  return r.v;
}

// Block-level sum/sumsq reduction -> ONE atomic pair per block (R4 lesson)
__device__ __forceinline__ void blockRedAtomic(float s, float sq, float* base) {
  __shared__ float red[32];
#pragma unroll
  for (int off = 32; off > 0; off >>= 1) {
    s  += __shfl_down(s, off, 64);
    sq += __shfl_down(sq, off, 64);
  }
  int wave = threadIdx.x >> 6;
  int nw = blockDim.x >> 6;
  if ((threadIdx.x & 63) == 0) { red[wave*2] = s; red[wave*2+1] = sq; }
  __syncthreads();
  if (threadIdx.x == 0) {
    float ts = 0.f, tq = 0.f;
    for (int i = 0; i < nw; ++i) { ts += red[i*2]; tq += red[i*2+1]; }
    unsafeAtomicAdd(base,     ts);
    unsafeAtomicAdd(base + 1, tq);
  }
}

// ---------------- init: block b zeros its stats slice + computes mask len ----
__global__ __launch_bounds__(256) void k_init(const float* __restrict__ mask,
                                              float* __restrict__ stats,
                                              int* __restrict__ lenbuf) {
  __shared__ int csh;
  int b = blockIdx.x, tid = threadIdx.x;
  if (tid == 0) csh = 0;
  // zero this block's slice of the 6*STATS_R stats region (3072 floats / 32)
  for (int i = tid; i < 96; i += 256) stats[b*96 + i] = 0.f;
  __syncthreads();
  int cnt = 0;
  for (int i = tid; i < NL; i += 256) cnt += (mask[(size_t)b*NL + i] == 0.f) ? 1 : 0;
#pragma unroll
  for (int off = 32; off > 0; off >>= 1) cnt += __shfl_down(cnt, off, 64);
  if ((tid & 63) == 0) atomicAdd(&csh, cnt);
  __syncthreads();
  if (tid == 0) lenbuf[b] = csh;
}

// ---------------- res16 = bf16(x + pos_enc); stats region 0 ----------
__global__ __launch_bounds__(256) void k_addpos(const float* __restrict__ x,
                                                const float* __restrict__ pe,
                                                u16* __restrict__ res,
                                                float* __restrict__ stats0) {
  int b = blockIdx.x >> 6;
  int off = ((blockIdx.x & 63) << 11) + (threadIdx.x << 3);
  const float4* xp = (const float4*)(x + (size_t)b*NDL + off);
  const float4* pp = (const float4*)(pe + off);
  float s = 0.f, sq = 0.f;
  float rv[8];
#pragma unroll
  for (int i = 0; i < 2; ++i) {
    float4 a = xp[i], p = pp[i];
    rv[i*4+0] = a.x + p.x; rv[i*4+1] = a.y + p.y;
    rv[i*4+2] = a.z + p.z; rv[i*4+3] = a.w + p.w;
  }
#pragma unroll
  for (int j = 0; j < 8; ++j) { s += rv[j]; sq += rv[j]*rv[j]; }
  uint4 pk;
  pk.x = packpair(rv[0], rv[1]); pk.y = packpair(rv[2], rv[3]);
  pk.z = packpair(rv[4], rv[5]); pk.w = packpair(rv[6], rv[7]);
  *(uint4*)(res + (size_t)b*NDL + off) = pk;
  blockRedAtomic(s, sq, stats0 + b*STATS_B);
}

// ============ MFMA GEMM — R13/R16 config (64-l tiles, 512 thr / 8 waves) ======
// Settled config after R11 (split-K lost), R12 (32-l lost), R14/R17 (1024-thr
// l-split lost): 512 thr, natural VGPR ~60, no min-waves force (R15: forcing
// spilled to scratch). xs layout (u32 = 2 bf16 along c):
// xs[(l<<6) | (c2 ^ ((l&7)<<2))]; frag read byte off =
// (l*256 + kk*64 + hi*16) ^ ((lo&7)<<4) (conflict-free).

__device__ __forceinline__ void load_w_frags16(const float* __restrict__ W,
                                               int wo, int lo, int hi, bf16x8 af[4]) {
#pragma unroll
  for (int kk = 0; kk < 4; ++kk) {
    const float4* wp = (const float4*)(W + (size_t)(wo + lo)*128 + kk*32 + hi*8);
    af[kk] = packbf8(wp[0], wp[1]);
  }
}

__device__ __forceinline__ void mfma_core16(const unsigned* xs, bf16x8 af[4],
                                            int lo, int hi, f32x4 acc[4]) {
#pragma unroll
  for (int ln = 0; ln < 4; ++ln) {
#pragma unroll
    for (int kk = 0; kk < 4; ++kk) {
      int l = ln*16 + lo;
      int off = (l*256 + kk*64 + hi*16) ^ ((lo & 7) << 4);
      bf16x8 bf = *(const bf16x8*)((const char*)xs + off);
      acc[ln] = mfma_bf16_16x16x32(af[kk], bf, acc[ln]);
    }
  }
}

// LN + depthwise-7 conv, bf16 source row, 8 outputs starting at `base`.
__device__ __forceinline__ void conv_row8(const u16* __restrict__ srow,
                                          const float* __restrict__ lwrow,
                                          const float* __restrict__ lbrow,
                                          int base, float mu, float rstd,
                                          const float* wk, float bias0,
                                          float* h /*[8]*/) {
  float wa[14];
  bool interior = (base >= 4) && (base + 12 <= NL);
  if (interior) {
    const uint2* sp = (const uint2*)(srow + base - 4);
    const float4* wp = (const float4*)(lwrow + base - 4);
    const float4* bp = (const float4*)(lbrow + base - 4);
#pragma unroll
    for (int qd = 0; qd < 4; ++qd) {
      uint2 sv2 = sp[qd];
      float4 w4 = wp[qd], b4 = bp[qd];
      float sv[4] = {bf2f((u16)(sv2.x & 0xFFFF)), bf2f((u16)(sv2.x >> 16)),
                     bf2f((u16)(sv2.y & 0xFFFF)), bf2f((u16)(sv2.y >> 16))};
      float wv[4] = {w4.x, w4.y, w4.z, w4.w};
      float bv[4] = {b4.x, b4.y, b4.z, b4.w};
#pragma unroll
      for (int e = 0; e < 4; ++e) {
        int j = qd*4 + e - 1;
        if (j >= 0 && j < 14)
          wa[j] = (sv[e] - mu)*rstd*wv[e] + bv[e];
      }
    }
  } else {
#pragma unroll
    for (int j = 0; j < 14; ++j) {
      int gl = base + j - 3;
      float v = 0.f;
      if (gl >= 0 && gl < NL)
        v = (bf2f(srow[gl]) - mu)*rstd*lwrow[gl] + lbrow[gl];
      wa[j] = v;
    }
  }
#pragma unroll
  for (int l = 0; l < 8; ++l) {
    float acc = bias0;
#pragma unroll
    for (int j = 0; j < 7; ++j) acc += wa[l+j]*wk[j];
    h[l] = acc;
  }
}

// MODE 0: wr16 = bf16(relu(W @ dwconv(LN(src16)) + bias) + res16)  (+stats)
// MODE 1: wr16 = bf16((W@src16 + bias) + res16)                     (+stats)
// MODE 3: outf = relu(W@LN(src16) + bias) + res16                   (f32 out)
template<int MODE>
__global__ __launch_bounds__(512) void k_gemm_mfma(
    const u16* __restrict__ src16, const float* __restrict__ W,
    const float* __restrict__ bias,
    const u16* __restrict__ res16, u16* __restrict__ wr16,
    float* __restrict__ outf,
    const float* __restrict__ lnw, const float* __restrict__ lnb,
    const float* __restrict__ dww, const float* __restrict__ dwb,
    const float* __restrict__ statsIn, float* __restrict__ statsOut) {
  __shared__ unsigned xs[4096];   // 16 KB: 64 l x 128 c bf16
  int b  = blockIdx.x >> 4;
  int l0 = (blockIdx.x & 15) << 6;
  int tid = threadIdx.x;
  int wave = tid >> 6, lane = tid & 63;
  int lo = lane & 15, hi = lane >> 4;
  int wo = wave * 16;

  float mu = 0.f, rstd = 0.f;
  if (MODE == 0 || MODE == 3) {
    mu = statsIn[b*STATS_B] * (1.f/NDL);
    rstd = rsqrtf(statsIn[b*STATS_B + 1]*(1.f/NDL) - mu*mu + 1e-5f);
  }

  if (MODE == 0) {
    int c2 = tid >> 3, lq = tid & 7;
    int c = c2*2, base = l0 + lq*8;
    float wk0[7], wk1[7];
#pragma unroll
    for (int j = 0; j < 7; ++j) { wk0[j] = dww[c*7 + j]; wk1[j] = dww[(c+1)*7 + j]; }
    const u16* sa = src16 + (size_t)b*NDL + (size_t)c*NL;
    const float* la  = lnw + (size_t)c*NL;
    const float* lbv = lnb + (size_t)c*NL;
    float h0[8], h1[8];
    conv_row8(sa,      la,      lbv,      base, mu, rstd, wk0, dwb[c],   h0);
    conv_row8(sa + NL, la + NL, lbv + NL, base, mu, rstd, wk1, dwb[c+1], h1);
#pragma unroll
    for (int l = 0; l < 8; ++l) {
      int ll = lq*8 + l;
      xs[(ll << 6) | (c2 ^ ((ll & 7) << 2))] = packpair(h0[l], h1[l]);
    }
  } else if (MODE == 1) {
    for (int i = tid; i < 1024; i += 512) {
      int c2 = i >> 4, lq = (i & 15) << 2;
      int c = c2*2;
      const u16* sp = src16 + (size_t)b*NDL + (size_t)c*NL + l0 + lq;
      uint2 ra = *(const uint2*)sp;
      uint2 rb = *(const uint2*)(sp + NL);
      unsigned wv[4];
      wv[0] = (ra.x & 0xFFFFu) | (rb.x << 16);
      wv[1] = (ra.x >> 16)     | (rb.x & 0xFFFF0000u);
      wv[2] = (ra.y & 0xFFFFu) | (rb.y << 16);
      wv[3] = (ra.y >> 16)     | (rb.y & 0xFFFF0000u);
#pragma unroll
      for (int j = 0; j < 4; ++j) {
        int l = lq + j;
        xs[(l << 6) | (c2 ^ ((l & 7) << 2))] = wv[j];
      }
    }
  } else {
    for (int i = tid; i < 1024; i += 512) {
      int c2 = i >> 4, lq = (i & 15) << 2;
      int c = c2*2;
      const u16* sp = src16 + (size_t)b*NDL + (size_t)c*NL + l0 + lq;
      uint2 ra = *(const uint2*)sp;
      uint2 rb = *(const uint2*)(sp + NL);
      float sa[4] = {bf2f((u16)(ra.x & 0xFFFF)), bf2f((u16)(ra.x >> 16)),
                     bf2f((u16)(ra.y & 0xFFFF)), bf2f((u16)(ra.y >> 16))};
      float sb[4] = {bf2f((u16)(rb.x & 0xFFFF)), bf2f((u16)(rb.x >> 16)),
                     bf2f((u16)(rb.y & 0xFFFF)), bf2f((u16)(rb.y >> 16))};
      size_t gi = (size_t)c*NL + l0 + lq;
      float4 w0 = *(const float4*)(lnw + gi), w1 = *(const float4*)(lnw + gi + NL);
      float4 bb0 = *(const float4*)(lnb + gi), bb1 = *(const float4*)(lnb + gi + NL);
      float va[4] = {(sa[0]-mu)*rstd*w0.x + bb0.x, (sa[1]-mu)*rstd*w0.y + bb0.y,
                     (sa[2]-mu)*rstd*w0.z + bb0.z, (sa[3]-mu)*rstd*w0.w + bb0.w};
      float vb[4] = {(sb[0]-mu)*rstd*w1.x + bb1.x, (sb[1]-mu)*rstd*w1.y + bb1.y,
                     (sb[2]-mu)*rstd*w1.z + bb1.z, (sb[3]-mu)*rstd*w1.w + bb1.w};
#pragma unroll
      for (int j = 0; j < 4; ++j) {
        int l = lq + j;
        xs[(l << 6) | (c2 ^ ((l & 7) << 2))] = packpair(va[j], vb[j]);
      }
    }
  }

  // prefetch residual (R13: hide epilogue HBM latency under staging+MFMA)
  u16 rpre[16];
#pragma unroll
  for (int ln = 0; ln < 4; ++ln)
#pragma unroll
    for (int r = 0; r < 4; ++r)
      rpre[ln*4+r] = res16[((size_t)b*ND + wo + hi*4 + r)*NL + l0 + ln*16 + lo];

  bf16x8 af[4];
  load_w_frags16(W, wo, lo, hi, af);
  f32x4 acc[4];
#pragma unroll
  for (int ln = 0; ln < 4; ++ln) acc[ln] = (f32x4){0.f,0.f,0.f,0.f};

  __syncthreads();
  mfma_core16(xs, af, lo, hi, acc);

  if (MODE == 0 || MODE == 1) {
    float s = 0.f, sq = 0.f;
#pragma unroll
    for (int ln = 0; ln < 4; ++ln) {
      int l = l0 + ln*16 + lo;
#pragma unroll
      for (int r = 0; r < 4; ++r) {
        int o = wo + hi*4 + r;
        size_t gi = ((size_t)b*ND + o)*NL + l;
        float v = acc[ln][r] + bias[o];
        if (MODE == 0) v = fmaxf(v, 0.f);
        v += bf2f(rpre[ln*4+r]);
        wr16[gi] = bf16rnd(v);
        s += v; sq += v*v;
      }
    }
    blockRedAtomic(s, sq, statsOut + b*STATS_B);
  } else {
#pragma unroll
    for (int ln = 0; ln < 4; ++ln) {
      int l = l0 + ln*16 + lo;
#pragma unroll
      for (int r = 0; r < 4; ++r) {
        int o = wo + hi*4 + r;
        size_t gi = ((size_t)b*ND + o)*NL + l;
        outf[gi] = fmaxf(acc[ln][r] + bias[o], 0.f) + bf2f(rpre[ln*4+r]);
      }
    }
  }
}

// Fused QKV (R13/R16 config): stage LN(bf16 src) once, 3 GEMMs, bf16 out.
// q scaled by 0.25*log2e so attention uses raw HW exp2.
__global__ __launch_bounds__(512) void k_qkv_mfma(
    const u16* __restrict__ src16,
    const float* __restrict__ qw, const float* __restrict__ kw, const float* __restrict__ vw,
    const float* __restrict__ qb, const float* __restrict__ kb, const float* __restrict__ vb,
    u16* __restrict__ qo, u16* __restrict__ ko, u16* __restrict__ vo,
    const float* __restrict__ lnw, const float* __restrict__ lnb,
    const float* __restrict__ statsIn) {
  __shared__ unsigned xs[4096];
  int b  = blockIdx.x >> 4;
  int l0 = (blockIdx.x & 15) << 6;
  int tid = threadIdx.x;
  int wave = tid >> 6, lane = tid & 63;
  int lo = lane & 15, hi = lane >> 4;
  int wo = wave * 16;

  float mu = statsIn[b*STATS_B] * (1.f/NDL);
  float rstd = rsqrtf(statsIn[b*STATS_B + 1]*(1.f/NDL) - mu*mu + 1e-5f);
  for (int i = tid; i < 1024; i += 512) {
    int c2 = i >> 4, lq = (i & 15) << 2;
    int c = c2*2;
    const u16* sp = src16 + (size_t)b*NDL + (size_t)c*NL + l0 + lq;
    uint2 ra = *(const uint2*)sp;
    uint2 rb = *(const uint2*)(sp + NL);
    float sa[4] = {bf2f((u16)(ra.x & 0xFFFF)), bf2f((u16)(ra.x >> 16)),
                   bf2f((u16)(ra.y & 0xFFFF)), bf2f((u16)(ra.y >> 16))};
    float sb[4] = {bf2f((u16)(rb.x & 0xFFFF)), bf2f((u16)(rb.x >> 16)),
                   bf2f((u16)(rb.y & 0xFFFF)), bf2f((u16)(rb.y >> 16))};
    size_t gi = (size_t)c*NL + l0 + lq;
    float4 w0 = *(const float4*)(lnw + gi), w1 = *(const float4*)(lnw + gi + NL);
    float4 bb0 = *(const float4*)(lnb + gi), bb1 = *(const float4*)(lnb + gi + NL);
    float va[4] = {(sa[0]-mu)*rstd*w0.x + bb0.x, (sa[1]-mu)*rstd*w0.y + bb0.y,
                   (sa[2]-mu)*rstd*w0.z + bb0.z, (sa[3]-mu)*rstd*w0.w + bb0.w};
    float vb4[4] = {(sb[0]-mu)*rstd*w1.x + bb1.x, (sb[1]-mu)*rstd*w1.y + bb1.y,
                    (sb[2]-mu)*rstd*w1.z + bb1.z, (sb[3]-mu)*rstd*w1.w + bb1.w};
#pragma unroll
    for (int j = 0; j < 4; ++j) {
      int l = lq + j;
      xs[(l << 6) | (c2 ^ ((l & 7) << 2))] = packpair(va[j], vb4[j]);
    }
  }
  __syncthreads();

  const float* Ws[3] = {qw, kw, vw};
  const float* Bs[3] = {qb, kb, vb};
  u16* Os[3] = {qo, ko, vo};
#pragma unroll 1
  for (int mat = 0; mat < 3; ++mat) {
    bf16x8 af[4];
    load_w_frags16(Ws[mat], wo, lo, hi, af);
    f32x4 acc[4];
#pragma unroll
    for (int ln = 0; ln < 4; ++ln) acc[ln] = (f32x4){0.f,0.f,0.f,0.f};
    mfma_core16(xs, af, lo, hi, acc);
    float oscale = (mat == 0) ? 0.25f*1.4426950408889634f : 1.0f;
    const float* bias = Bs[mat];
    u16* op = Os[mat];
#pragma unroll
    for (int ln = 0; ln < 4; ++ln) {
      int l = l0 + ln*16 + lo;
      int o4 = wo + hi*4;
      float vx = (acc[ln][0] + bias[o4+0]) * oscale;
      float vy = (acc[ln][1] + bias[o4+1]) * oscale;
      float vz = (acc[ln][2] + bias[o4+2]) * oscale;
      float vw4 = (acc[ln][3] + bias[o4+3]) * oscale;
      uint2 pk; pk.x = packpair(vx, vy); pk.y = packpair(vz, vw4);
      *(uint2*)(op + ((size_t)b*NL + l)*ND + o4) = pk;
    }
  }
}

// ---------------- fused MFMA attention (quarter-split, V-only LDS) ------------
// R16 config: 2048 blocks x 512 thr, natural VGPR 40 (no min-waves force —
// R15: forcing spilled), Occ ~41%, 53.6 us.
template<bool MASKED>
__device__ __forceinline__ void attn_tile(bf16x8 kf0, bf16x8 kf1, bf16x8 vf,
                                          bf16x8 onesf, const bf16x8 qf[2],
                                          f32x4 acc[2], f32x4 dacc[2],
                                          int kb, int len, int hi) {
#pragma unroll
  for (int qt = 0; qt < 2; ++qt) {
    f32x4 z = (f32x4){0.f,0.f,0.f,0.f};
    f32x4 s0 = mfma_bf16_16x16x32(kf0, qf[qt], z);
    f32x4 s1 = mfma_bf16_16x16x32(kf1, qf[qt], z);
    float e[8];
#pragma unroll
    for (int r = 0; r < 4; ++r) {
      float e0 = exp2fast(s0[r]);
      float e1 = exp2fast(s1[r]);
      if (MASKED) {
        e0 = (kb + hi*4 + r < len)      ? e0 : 0.f;
        e1 = (kb + 16 + hi*4 + r < len) ? e1 : 0.f;
      }
      e[r] = e0; e[r+4] = e1;
    }
    union { unsigned u[4]; bf16x8 v; } pu;
    pu.u[0] = packtrunc(e[0], e[1]);
    pu.u[1] = packtrunc(e[2], e[3]);
    pu.u[2] = packtrunc(e[4], e[5]);
    pu.u[3] = packtrunc(e[6], e[7]);
    acc[qt]  = mfma_bf16_16x16x32(vf,    pu.v, acc[qt]);
    dacc[qt] = mfma_bf16_16x16x32(onesf, pu.v, dacc[qt]);
  }
}

__device__ __forceinline__ bf16x8 ldKrow(const u16* kbase, int key, int hi) {
  union { uint4 u; bf16x8 v; } r;
  r.u = *(const uint4*)(kbase + (size_t)key*ND + hi*8);
  return r.v;
}

__global__ __launch_bounds__(512) void k_attn_fused(
    const u16* __restrict__ q, const u16* __restrict__ k,
    const u16* __restrict__ v, const int* __restrict__ lenbuf,
    u16* __restrict__ att_t) {
  __shared__ short kv[16384];   // 32 KB: V fragments only
  int bid = blockIdx.x;
  int b  = bid >> 5;
  int h  = (bid >> 2) & 7;
  int qq = bid & 3;
  int tid = threadIdx.x;
  int len = lenbuf[b];
  int nkt = (len + 31) >> 5;
  int kstage = nkt << 5;

  // ---- stage V: (key-pair, d-quad) tasks; interleave two key rows
  for (int idx = tid; idx < 2048; idx += 512) {
    int keyp = idx >> 2, vq = idx & 3;
    int key = keyp*2;
    if (key >= kstage) break;
    int vlo = vq*4;
    uint2 ra, rb; ra.x = ra.y = rb.x = rb.y = 0u;
    size_t voff = ((size_t)b*NL + key)*ND + h*16 + vlo;
    if (key < len)     ra = *(const uint2*)(v + voff);
    if (key + 1 < len) rb = *(const uint2*)(v + voff + ND);
    unsigned wv[4];
    wv[0] = (ra.x & 0xFFFFu) | (rb.x << 16);
    wv[1] = (ra.x >> 16)     | (rb.x & 0xFFFF0000u);
    wv[2] = (ra.y & 0xFFFFu) | (rb.y << 16);
    wv[3] = (ra.y >> 16)     | (rb.y & 0xFFFF0000u);
    int kt = key >> 5, w = key & 31;  // even
    int vhi, ii;
    if (w < 16) { vhi = w >> 2; ii = w & 3; }
    else        { vhi = (w - 16) >> 2; ii = 4 + (w & 3); }
#pragma unroll
    for (int e = 0; e < 4; ++e)
      *(unsigned*)(kv + kt*512 + (vhi*16 + vlo + e)*8 + ii) = wv[e];
  }
  __syncthreads();

  int wave = tid >> 6, lane = tid & 63;
  int lo = lane & 15, hi = lane >> 4;
  int q0 = qq*256 + wave*32;

  bf16x8 qf[2];
#pragma unroll
  for (int qt = 0; qt < 2; ++qt) {
    if (hi < 2) {
      union { uint4 u; bf16x8 v; } qu;
      qu.u = *(const uint4*)(q + ((size_t)b*NL + q0 + qt*16 + lo)*ND + h*16 + hi*8);
      qf[qt] = qu.v;
    } else {
      qf[qt] = (bf16x8){0,0,0,0,0,0,0,0};
    }
  }
  const short oneb = (short)0x3F80;   // bf16 1.0
  bf16x8 onesf = (bf16x8){oneb,oneb,oneb,oneb,oneb,oneb,oneb,oneb};
  f32x4 acc[2], dacc[2];
#pragma unroll
  for (int qt = 0; qt < 2; ++qt) {
    acc[qt]  = (f32x4){0.f,0.f,0.f,0.f};
    dacc[qt] = (f32x4){0.f,0.f,0.f,0.f};
  }

  int fullt = len >> 5;
  const u16* kbase = k + (size_t)b*NL*ND + h*16;

  // register double-buffer: K direct from global (L2), V from LDS
  bf16x8 cka = (bf16x8){0,0,0,0,0,0,0,0}, ckb = cka, cv;
  if (hi < 2) {
    cka = ldKrow(kbase, lo, hi);
    ckb = ldKrow(kbase, 16 + lo, hi);
  }
  cv = *(const bf16x8*)(kv + lane*8);

  for (int kt = 0; kt < nkt; ++kt) {
    bf16x8 nka = cka, nkb = ckb, nv = cv;
    if (kt + 1 < nkt) {
      int kb2 = (kt+1)*32;
      if (hi < 2) {
        nka = ldKrow(kbase, kb2 + lo, hi);
        nkb = ldKrow(kbase, kb2 + 16 + lo, hi);
      }
      nv = *(const bf16x8*)(kv + (kt+1)*512 + lane*8);
    }
    if (kt < fullt) attn_tile<false>(cka, ckb, cv, onesf, qf, acc, dacc, kt*32, len, hi);
    else            attn_tile<true >(cka, ckb, cv, onesf, qf, acc, dacc, kt*32, len, hi);
    cka = nka; ckb = nkb; cv = nv;
  }
#pragma unroll
  for (int qt = 0; qt < 2; ++qt) {
    float inv = 1.f / dacc[qt][0];   // every C-row of ones-MFMA = full row-sum
    size_t obase = ((size_t)b*ND + h*16)*NL + q0 + qt*16 + lo;
#pragma unroll
    for (int r = 0; r < 4; ++r)
      att_t[obase + (size_t)(hi*4 + r)*NL] = bf16rnd(acc[qt][r] * inv);
  }
}

// ---------------- launcher ----------------
extern "C" void kernel_launch(void* const* d_in, const int* in_sizes, int n_in,
                              void* d_out, int out_size, void* d_ws, size_t ws_size,
                              hipStream_t stream) {
  (void)in_sizes; (void)n_in; (void)out_size; (void)ws_size;
  const float* x       = (const float*)d_in[0];
  const float* mask    = (const float*)d_in[1];
  const float* pe      = (const float*)d_in[2];
  const float* normb_w = (const float*)d_in[3];
  const float* normb_b = (const float*)d_in[4];
  const float* dw_w    = (const float*)d_in[5];
  const float* dw_b    = (const float*)d_in[6];
  const float* pw_w    = (const float*)d_in[7];
  const float* pw_b    = (const float*)d_in[8];
  const float* norms_w = (const float*)d_in[9];
  const float* norms_b = (const float*)d_in[10];
  const float* qw      = (const float*)d_in[11];
  const float* qb      = (const float*)d_in[12];
  const float* kw      = (const float*)d_in[13];
  const float* kb      = (const float*)d_in[14];
  const float* vw      = (const float*)d_in[15];
  const float* vb      = (const float*)d_in[16];
  const float* aw      = (const float*)d_in[17];
  const float* ab      = (const float*)d_in[18];
  const float* norme_w = (const float*)d_in[19];
  const float* norme_b = (const float*)d_in[20];
  const float* fw      = (const float*)d_in[21];
  const float* fb      = (const float*)d_in[22];

  float* out = (float*)d_out;
  float* ws  = (float*)d_ws;
  const size_t NT = (size_t)NB*ND*NL;   // element count per (B,D,L) tensor
  u16* resA = (u16*)ws;                  // NT bf16 = NT/2 floats
  u16* resB = (u16*)(ws + NT/2);
  u16* qb16 = (u16*)(ws + NT);
  u16* kb16 = (u16*)(ws + 3*NT/2);
  u16* vb16 = (u16*)(ws + 2*NT);
  float* stats = ws + 3*NT;              // 6 * STATS_R floats
  int* lenbuf = (int*)(stats + 6*STATS_R);
  u16* att16 = resB;                     // resB free after conv chain

  k_init<<<dim3(NB), dim3(256), 0, stream>>>(mask, stats, lenbuf);
  k_addpos<<<dim3(2048), dim3(256), 0, stream>>>(x, pe, resA, stats);

  // conv layers ping-pong A->B->A->B->A (halo reads never race with writes)
  for (int i = 0; i < 4; ++i) {
    const float* lw = (i == 0) ? normb_w : norms_w + (size_t)(i-1)*NDL;
    const float* lb = (i == 0) ? normb_b : norms_b + (size_t)(i-1)*NDL;
    const u16* rsrc = (i & 1) ? resB : resA;
    u16*       rdst = (i & 1) ? resA : resB;
    k_gemm_mfma<0><<<dim3(NB*16), dim3(512), 0, stream>>>(
        rsrc, pw_w + i*ND*ND, pw_b + i*ND, rsrc, rdst, nullptr,
        lw, lb, dw_w + i*ND*7, dw_b + i*ND,
        stats + i*STATS_R, stats + (i+1)*STATS_R);
  }
  // after 4 layers res lives in resA

  const float* ln3w = norms_w + (size_t)3*NDL;
  const float* ln3b = norms_b + (size_t)3*NDL;
  k_qkv_mfma<<<dim3(NB*16), dim3(512), 0, stream>>>(
      resA, qw, kw, vw, qb, kb, vb, qb16, kb16, vb16, ln3w, ln3b, stats + 4*STATS_R);

  k_attn_fused<<<dim3(NB*8*4), dim3(512), 0, stream>>>(qb16, kb16, vb16, lenbuf, att16);

  // attn out proj: bf16 src, residual resA, in-place (no halo -> safe)
  k_gemm_mfma<1><<<dim3(NB*16), dim3(512), 0, stream>>>(
      att16, aw, ab, resA, resA, nullptr, nullptr, nullptr, nullptr, nullptr,
      nullptr, stats + 5*STATS_R);
  k_gemm_mfma<3><<<dim3(NB*16), dim3(512), 0, stream>>>(
      resA, fw, fb, resA, nullptr, out, norme_w, norme_b, nullptr, nullptr,
      stats + 5*STATS_R, nullptr);
}

// Round 19
// 166.173 us; speedup vs baseline: 1.2904x; 1.0081x over previous
//
#include <hip/hip_runtime.h>

#define NB 32
#define ND 128
#define NL 1024
#define NDL (ND*NL)   // 131072 per batch
// stats: 6 regions x 32 batches x 16 floats (one 64B cacheline per (r,b))
#define STATS_B 16
#define STATS_R (32*STATS_B)

typedef __attribute__((ext_vector_type(8))) short bf16x8;
typedef __attribute__((ext_vector_type(4))) float f32x4;
typedef unsigned short u16;

__device__ __forceinline__ f32x4 mfma_bf16_16x16x32(bf16x8 a, bf16x8 b, f32x4 c) {
#if defined(__HIP_DEVICE_COMPILE__)
  return __builtin_amdgcn_mfma_f32_16x16x32_bf16(a, b, c, 0, 0, 0);
#else
  return c;
#endif
}

// HW exp2 via BUILTIN (R8 lesson: raw asm hides TRANS hazard -> NaN)
__device__ __forceinline__ float exp2fast(float x) {
#if defined(__HIP_DEVICE_COMPILE__) && __has_builtin(__builtin_amdgcn_exp2f)
  return __builtin_amdgcn_exp2f(x);
#elif defined(__HIP_DEVICE_COMPILE__)
  return __expf(x * 0.6931471805599453f);
#else
  return x;
#endif
}

// bf16 <-> f32 primitives (R7: avoid library cvt NaN-paths; shift is 1 op)
__device__ __forceinline__ float bf2f(u16 u) {
  union { unsigned u; float f; } c; c.u = ((unsigned)u) << 16; return c.f;
}
__device__ __forceinline__ u16 bf16rnd(float f) {
  union { float f; unsigned u; } c; c.f = f;
  return (u16)((c.u + 0x7FFFu + ((c.u >> 16) & 1u)) >> 16);
}
__device__ __forceinline__ unsigned packpair(float a, float b) {
  return (unsigned)bf16rnd(a) | ((unsigned)bf16rnd(b) << 16);
}
// 3-op truncating pack for attention P (R9: trunc bias ~0.2%, headroom allows)
__device__ __forceinline__ unsigned packtrunc(float a, float b) {
  unsigned ua = __float_as_uint(a), ub = __float_as_uint(b);
  return (ub & 0xFFFF0000u) | (ua >> 16);
}
__device__ __forceinline__ bf16x8 packbf8(float4 a, float4 b) {
  union { unsigned u[4]; bf16x8 v; } r;
  r.u[0] = packpair(a.x, a.y); r.u[1] = packpair(a.z, a.w);
  r.u[2] = packpair(b.x, b.y); r.u[3] = packpair(b.z, b.w);
  return r.v;
}

// Block-level sum/sumsq reduction -> ONE atomic pair per block (R4 lesson)
__device__ __forceinline__ void blockRedAtomic(float s, float sq, float* base) {
  __shared__ float red[32];
#pragma unroll
  for (int off = 32; off > 0; off >>= 1) {
    s  += __shfl_down(s, off, 64);
    sq += __shfl_down(sq, off, 64);
  }
  int wave = threadIdx.x >> 6;
  int nw = blockDim.x >> 6;
  if ((threadIdx.x & 63) == 0) { red[wave*2] = s; red[wave*2+1] = sq; }
  __syncthreads();
  if (threadIdx.x == 0) {
    float ts = 0.f, tq = 0.f;
    for (int i = 0; i < nw; ++i) { ts += red[i*2]; tq += red[i*2+1]; }
    unsafeAtomicAdd(base,     ts);
    unsafeAtomicAdd(base + 1, tq);
  }
}

// ---------------- init: block b zeros its stats slice + computes mask len ----
__global__ __launch_bounds__(256) void k_init(const float* __restrict__ mask,
                                              float* __restrict__ stats,
                                              int* __restrict__ lenbuf) {
  __shared__ int csh;
  int b = blockIdx.x, tid = threadIdx.x;
  if (tid == 0) csh = 0;
  for (int i = tid; i < 96; i += 256) stats[b*96 + i] = 0.f;
  __syncthreads();
  int cnt = 0;
  for (int i = tid; i < NL; i += 256) cnt += (mask[(size_t)b*NL + i] == 0.f) ? 1 : 0;
#pragma unroll
  for (int off = 32; off > 0; off >>= 1) cnt += __shfl_down(cnt, off, 64);
  if ((tid & 63) == 0) atomicAdd(&csh, cnt);
  __syncthreads();
  if (tid == 0) lenbuf[b] = csh;
}

// ---------------- rank-sort batches by len DESC -> order[] (R18 tail fix) ----
// Longest batches dispatch first; short blocks form the tail and pack better.
__global__ void k_order(const int* __restrict__ lenbuf, int* __restrict__ order) {
  int t = threadIdx.x;   // 32 threads
  int mylen = lenbuf[t];
  int rank = 0;
  for (int j = 0; j < NB; ++j) {
    int lj = lenbuf[j];
    rank += (lj > mylen || (lj == mylen && j < t)) ? 1 : 0;
  }
  order[rank] = t;
}

// ---------------- res16 = bf16(x + pos_enc); stats region 0 ----------
__global__ __launch_bounds__(256) void k_addpos(const float* __restrict__ x,
                                                const float* __restrict__ pe,
                                                u16* __restrict__ res,
                                                float* __restrict__ stats0) {
  int b = blockIdx.x >> 6;
  int off = ((blockIdx.x & 63) << 11) + (threadIdx.x << 3);
  const float4* xp = (const float4*)(x + (size_t)b*NDL + off);
  const float4* pp = (const float4*)(pe + off);
  float s = 0.f, sq = 0.f;
  float rv[8];
#pragma unroll
  for (int i = 0; i < 2; ++i) {
    float4 a = xp[i], p = pp[i];
    rv[i*4+0] = a.x + p.x; rv[i*4+1] = a.y + p.y;
    rv[i*4+2] = a.z + p.z; rv[i*4+3] = a.w + p.w;
  }
#pragma unroll
  for (int j = 0; j < 8; ++j) { s += rv[j]; sq += rv[j]*rv[j]; }
  uint4 pk;
  pk.x = packpair(rv[0], rv[1]); pk.y = packpair(rv[2], rv[3]);
  pk.z = packpair(rv[4], rv[5]); pk.w = packpair(rv[6], rv[7]);
  *(uint4*)(res + (size_t)b*NDL + off) = pk;
  blockRedAtomic(s, sq, stats0 + b*STATS_B);
}

// ============ MFMA GEMM — settled config (64-l tiles, 512 thr / 8 waves) ======
// After R11 (split-K lost), R12 (32-l lost), R14/R17 (l-split lost), R15
// (min-waves force spilled): 512 thr, natural VGPR ~60.
// xs layout (u32 = 2 bf16 along c): xs[(l<<6) | (c2 ^ ((l&7)<<2))];
// frag read byte off = (l*256 + kk*64 + hi*16) ^ ((lo&7)<<4) (conflict-free).

__device__ __forceinline__ void load_w_frags16(const float* __restrict__ W,
                                               int wo, int lo, int hi, bf16x8 af[4]) {
#pragma unroll
  for (int kk = 0; kk < 4; ++kk) {
    const float4* wp = (const float4*)(W + (size_t)(wo + lo)*128 + kk*32 + hi*8);
    af[kk] = packbf8(wp[0], wp[1]);
  }
}

__device__ __forceinline__ void mfma_core16(const unsigned* xs, bf16x8 af[4],
                                            int lo, int hi, f32x4 acc[4]) {
#pragma unroll
  for (int ln = 0; ln < 4; ++ln) {
#pragma unroll
    for (int kk = 0; kk < 4; ++kk) {
      int l = ln*16 + lo;
      int off = (l*256 + kk*64 + hi*16) ^ ((lo & 7) << 4);
      bf16x8 bf = *(const bf16x8*)((const char*)xs + off);
      acc[ln] = mfma_bf16_16x16x32(af[kk], bf, acc[ln]);
    }
  }
}

// LN + depthwise-7 conv, bf16 source row, 8 outputs starting at `base`.
__device__ __forceinline__ void conv_row8(const u16* __restrict__ srow,
                                          const float* __restrict__ lwrow,
                                          const float* __restrict__ lbrow,
                                          int base, float mu, float rstd,
                                          const float* wk, float bias0,
                                          float* h /*[8]*/) {
  float wa[14];
  bool interior = (base >= 4) && (base + 12 <= NL);
  if (interior) {
    const uint2* sp = (const uint2*)(srow + base - 4);
    const float4* wp = (const float4*)(lwrow + base - 4);
    const float4* bp = (const float4*)(lbrow + base - 4);
#pragma unroll
    for (int qd = 0; qd < 4; ++qd) {
      uint2 sv2 = sp[qd];
      float4 w4 = wp[qd], b4 = bp[qd];
      float sv[4] = {bf2f((u16)(sv2.x & 0xFFFF)), bf2f((u16)(sv2.x >> 16)),
                     bf2f((u16)(sv2.y & 0xFFFF)), bf2f((u16)(sv2.y >> 16))};
      float wv[4] = {w4.x, w4.y, w4.z, w4.w};
      float bv[4] = {b4.x, b4.y, b4.z, b4.w};
#pragma unroll
      for (int e = 0; e < 4; ++e) {
        int j = qd*4 + e - 1;
        if (j >= 0 && j < 14)
          wa[j] = (sv[e] - mu)*rstd*wv[e] + bv[e];
      }
    }
  } else {
#pragma unroll
    for (int j = 0; j < 14; ++j) {
      int gl = base + j - 3;
      float v = 0.f;
      if (gl >= 0 && gl < NL)
        v = (bf2f(srow[gl]) - mu)*rstd*lwrow[gl] + lbrow[gl];
      wa[j] = v;
    }
  }
#pragma unroll
  for (int l = 0; l < 8; ++l) {
    float acc = bias0;
#pragma unroll
    for (int j = 0; j < 7; ++j) acc += wa[l+j]*wk[j];
    h[l] = acc;
  }
}

// MODE 0: wr16 = bf16(relu(W @ dwconv(LN(src16)) + bias) + res16)  (+stats)
// MODE 1: wr16 = bf16((W@src16 + bias) + res16)                     (+stats)
// MODE 3: outf = relu(W@LN(src16) + bias) + res16                   (f32 out)
template<int MODE>
__global__ __launch_bounds__(512) void k_gemm_mfma(
    const u16* __restrict__ src16, const float* __restrict__ W,
    const float* __restrict__ bias,
    const u16* __restrict__ res16, u16* __restrict__ wr16,
    float* __restrict__ outf,
    const float* __restrict__ lnw, const float* __restrict__ lnb,
    const float* __restrict__ dww, const float* __restrict__ dwb,
    const float* __restrict__ statsIn, float* __restrict__ statsOut) {
  __shared__ unsigned xs[4096];   // 16 KB: 64 l x 128 c bf16
  int b  = blockIdx.x >> 4;
  int l0 = (blockIdx.x & 15) << 6;
  int tid = threadIdx.x;
  int wave = tid >> 6, lane = tid & 63;
  int lo = lane & 15, hi = lane >> 4;
  int wo = wave * 16;

  float mu = 0.f, rstd = 0.f;
  if (MODE == 0 || MODE == 3) {
    mu = statsIn[b*STATS_B] * (1.f/NDL);
    rstd = rsqrtf(statsIn[b*STATS_B + 1]*(1.f/NDL) - mu*mu + 1e-5f);
  }

  if (MODE == 0) {
    int c2 = tid >> 3, lq = tid & 7;
    int c = c2*2, base = l0 + lq*8;
    float wk0[7], wk1[7];
#pragma unroll
    for (int j = 0; j < 7; ++j) { wk0[j] = dww[c*7 + j]; wk1[j] = dww[(c+1)*7 + j]; }
    const u16* sa = src16 + (size_t)b*NDL + (size_t)c*NL;
    const float* la  = lnw + (size_t)c*NL;
    const float* lbv = lnb + (size_t)c*NL;
    float h0[8], h1[8];
    conv_row8(sa,      la,      lbv,      base, mu, rstd, wk0, dwb[c],   h0);
    conv_row8(sa + NL, la + NL, lbv + NL, base, mu, rstd, wk1, dwb[c+1], h1);
#pragma unroll
    for (int l = 0; l < 8; ++l) {
      int ll = lq*8 + l;
      xs[(ll << 6) | (c2 ^ ((ll & 7) << 2))] = packpair(h0[l], h1[l]);
    }
  } else if (MODE == 1) {
    for (int i = tid; i < 1024; i += 512) {
      int c2 = i >> 4, lq = (i & 15) << 2;
      int c = c2*2;
      const u16* sp = src16 + (size_t)b*NDL + (size_t)c*NL + l0 + lq;
      uint2 ra = *(const uint2*)sp;
      uint2 rb = *(const uint2*)(sp + NL);
      unsigned wv[4];
      wv[0] = (ra.x & 0xFFFFu) | (rb.x << 16);
      wv[1] = (ra.x >> 16)     | (rb.x & 0xFFFF0000u);
      wv[2] = (ra.y & 0xFFFFu) | (rb.y << 16);
      wv[3] = (ra.y >> 16)     | (rb.y & 0xFFFF0000u);
#pragma unroll
      for (int j = 0; j < 4; ++j) {
        int l = lq + j;
        xs[(l << 6) | (c2 ^ ((l & 7) << 2))] = wv[j];
      }
    }
  } else {
    for (int i = tid; i < 1024; i += 512) {
      int c2 = i >> 4, lq = (i & 15) << 2;
      int c = c2*2;
      const u16* sp = src16 + (size_t)b*NDL + (size_t)c*NL + l0 + lq;
      uint2 ra = *(const uint2*)sp;
      uint2 rb = *(const uint2*)(sp + NL);
      float sa[4] = {bf2f((u16)(ra.x & 0xFFFF)), bf2f((u16)(ra.x >> 16)),
                     bf2f((u16)(ra.y & 0xFFFF)), bf2f((u16)(ra.y >> 16))};
      float sb[4] = {bf2f((u16)(rb.x & 0xFFFF)), bf2f((u16)(rb.x >> 16)),
                     bf2f((u16)(rb.y & 0xFFFF)), bf2f((u16)(rb.y >> 16))};
      size_t gi = (size_t)c*NL + l0 + lq;
      float4 w0 = *(const float4*)(lnw + gi), w1 = *(const float4*)(lnw + gi + NL);
      float4 bb0 = *(const float4*)(lnb + gi), bb1 = *(const float4*)(lnb + gi + NL);
      float va[4] = {(sa[0]-mu)*rstd*w0.x + bb0.x, (sa[1]-mu)*rstd*w0.y + bb0.y,
                     (sa[2]-mu)*rstd*w0.z + bb0.z, (sa[3]-mu)*rstd*w0.w + bb0.w};
      float vb[4] = {(sb[0]-mu)*rstd*w1.x + bb1.x, (sb[1]-mu)*rstd*w1.y + bb1.y,
                     (sb[2]-mu)*rstd*w1.z + bb1.z, (sb[3]-mu)*rstd*w1.w + bb1.w};
#pragma unroll
      for (int j = 0; j < 4; ++j) {
        int l = lq + j;
        xs[(l << 6) | (c2 ^ ((l & 7) << 2))] = packpair(va[j], vb[j]);
      }
    }
  }

  // prefetch residual (R13: hide epilogue HBM latency under staging+MFMA)
  u16 rpre[16];
#pragma unroll
  for (int ln = 0; ln < 4; ++ln)
#pragma unroll
    for (int r = 0; r < 4; ++r)
      rpre[ln*4+r] = res16[((size_t)b*ND + wo + hi*4 + r)*NL + l0 + ln*16 + lo];

  bf16x8 af[4];
  load_w_frags16(W, wo, lo, hi, af);
  f32x4 acc[4];
#pragma unroll
  for (int ln = 0; ln < 4; ++ln) acc[ln] = (f32x4){0.f,0.f,0.f,0.f};

  __syncthreads();
  mfma_core16(xs, af, lo, hi, acc);

  if (MODE == 0 || MODE == 1) {
    float s = 0.f, sq = 0.f;
#pragma unroll
    for (int ln = 0; ln < 4; ++ln) {
      int l = l0 + ln*16 + lo;
#pragma unroll
      for (int r = 0; r < 4; ++r) {
        int o = wo + hi*4 + r;
        size_t gi = ((size_t)b*ND + o)*NL + l;
        float v = acc[ln][r] + bias[o];
        if (MODE == 0) v = fmaxf(v, 0.f);
        v += bf2f(rpre[ln*4+r]);
        wr16[gi] = bf16rnd(v);
        s += v; sq += v*v;
      }
    }
    blockRedAtomic(s, sq, statsOut + b*STATS_B);
  } else {
#pragma unroll
    for (int ln = 0; ln < 4; ++ln) {
      int l = l0 + ln*16 + lo;
#pragma unroll
      for (int r = 0; r < 4; ++r) {
        int o = wo + hi*4 + r;
        size_t gi = ((size_t)b*ND + o)*NL + l;
        outf[gi] = fmaxf(acc[ln][r] + bias[o], 0.f) + bf2f(rpre[ln*4+r]);
      }
    }
  }
}

// Fused QKV (settled config): stage LN(bf16 src) once, 3 GEMMs, bf16 out.
// q scaled by 0.25*log2e so attention uses raw HW exp2.
__global__ __launch_bounds__(512) void k_qkv_mfma(
    const u16* __restrict__ src16,
    const float* __restrict__ qw, const float* __restrict__ kw, const float* __restrict__ vw,
    const float* __restrict__ qb, const float* __restrict__ kb, const float* __restrict__ vb,
    u16* __restrict__ qo, u16* __restrict__ ko, u16* __restrict__ vo,
    const float* __restrict__ lnw, const float* __restrict__ lnb,
    const float* __restrict__ statsIn) {
  __shared__ unsigned xs[4096];
  int b  = blockIdx.x >> 4;
  int l0 = (blockIdx.x & 15) << 6;
  int tid = threadIdx.x;
  int wave = tid >> 6, lane = tid & 63;
  int lo = lane & 15, hi = lane >> 4;
  int wo = wave * 16;

  float mu = statsIn[b*STATS_B] * (1.f/NDL);
  float rstd = rsqrtf(statsIn[b*STATS_B + 1]*(1.f/NDL) - mu*mu + 1e-5f);
  for (int i = tid; i < 1024; i += 512) {
    int c2 = i >> 4, lq = (i & 15) << 2;
    int c = c2*2;
    const u16* sp = src16 + (size_t)b*NDL + (size_t)c*NL + l0 + lq;
    uint2 ra = *(const uint2*)sp;
    uint2 rb = *(const uint2*)(sp + NL);
    float sa[4] = {bf2f((u16)(ra.x & 0xFFFF)), bf2f((u16)(ra.x >> 16)),
                   bf2f((u16)(ra.y & 0xFFFF)), bf2f((u16)(ra.y >> 16))};
    float sb[4] = {bf2f((u16)(rb.x & 0xFFFF)), bf2f((u16)(rb.x >> 16)),
                   bf2f((u16)(rb.y & 0xFFFF)), bf2f((u16)(rb.y >> 16))};
    size_t gi = (size_t)c*NL + l0 + lq;
    float4 w0 = *(const float4*)(lnw + gi), w1 = *(const float4*)(lnw + gi + NL);
    float4 bb0 = *(const float4*)(lnb + gi), bb1 = *(const float4*)(lnb + gi + NL);
    float va[4] = {(sa[0]-mu)*rstd*w0.x + bb0.x, (sa[1]-mu)*rstd*w0.y + bb0.y,
                   (sa[2]-mu)*rstd*w0.z + bb0.z, (sa[3]-mu)*rstd*w0.w + bb0.w};
    float vb4[4] = {(sb[0]-mu)*rstd*w1.x + bb1.x, (sb[1]-mu)*rstd*w1.y + bb1.y,
                    (sb[2]-mu)*rstd*w1.z + bb1.z, (sb[3]-mu)*rstd*w1.w + bb1.w};
#pragma unroll
    for (int j = 0; j < 4; ++j) {
      int l = lq + j;
      xs[(l << 6) | (c2 ^ ((l & 7) << 2))] = packpair(va[j], vb4[j]);
    }
  }
  __syncthreads();

  const float* Ws[3] = {qw, kw, vw};
  const float* Bs[3] = {qb, kb, vb};
  u16* Os[3] = {qo, ko, vo};
#pragma unroll 1
  for (int mat = 0; mat < 3; ++mat) {
    bf16x8 af[4];
    load_w_frags16(Ws[mat], wo, lo, hi, af);
    f32x4 acc[4];
#pragma unroll
    for (int ln = 0; ln < 4; ++ln) acc[ln] = (f32x4){0.f,0.f,0.f,0.f};
    mfma_core16(xs, af, lo, hi, acc);
    float oscale = (mat == 0) ? 0.25f*1.4426950408889634f : 1.0f;
    const float* bias = Bs[mat];
    u16* op = Os[mat];
#pragma unroll
    for (int ln = 0; ln < 4; ++ln) {
      int l = l0 + ln*16 + lo;
      int o4 = wo + hi*4;
      float vx = (acc[ln][0] + bias[o4+0]) * oscale;
      float vy = (acc[ln][1] + bias[o4+1]) * oscale;
      float vz = (acc[ln][2] + bias[o4+2]) * oscale;
      float vw4 = (acc[ln][3] + bias[o4+3]) * oscale;
      uint2 pk; pk.x = packpair(vx, vy); pk.y = packpair(vz, vw4);
      *(uint2*)(op + ((size_t)b*NL + l)*ND + o4) = pk;
    }
  }
}

// ---------------- fused MFMA attention (quarter-split, V-only LDS) ------------
// R16 config + R18 tail fix: blocks map to batches via len-DESC order[] so
// long-len batches dispatch first and short blocks pack the tail.
template<bool MASKED>
__device__ __forceinline__ void attn_tile(bf16x8 kf0, bf16x8 kf1, bf16x8 vf,
                                          bf16x8 onesf, const bf16x8 qf[2],
                                          f32x4 acc[2], f32x4 dacc[2],
                                          int kb, int len, int hi) {
#pragma unroll
  for (int qt = 0; qt < 2; ++qt) {
    f32x4 z = (f32x4){0.f,0.f,0.f,0.f};
    f32x4 s0 = mfma_bf16_16x16x32(kf0, qf[qt], z);
    f32x4 s1 = mfma_bf16_16x16x32(kf1, qf[qt], z);
    float e[8];
#pragma unroll
    for (int r = 0; r < 4; ++r) {
      float e0 = exp2fast(s0[r]);
      float e1 = exp2fast(s1[r]);
      if (MASKED) {
        e0 = (kb + hi*4 + r < len)      ? e0 : 0.f;
        e1 = (kb + 16 + hi*4 + r < len) ? e1 : 0.f;
      }
      e[r] = e0; e[r+4] = e1;
    }
    union { unsigned u[4]; bf16x8 v; } pu;
    pu.u[0] = packtrunc(e[0], e[1]);
    pu.u[1] = packtrunc(e[2], e[3]);
    pu.u[2] = packtrunc(e[4], e[5]);
    pu.u[3] = packtrunc(e[6], e[7]);
    acc[qt]  = mfma_bf16_16x16x32(vf,    pu.v, acc[qt]);
    dacc[qt] = mfma_bf16_16x16x32(onesf, pu.v, dacc[qt]);
  }
}

__device__ __forceinline__ bf16x8 ldKrow(const u16* kbase, int key, int hi) {
  union { uint4 u; bf16x8 v; } r;
  r.u = *(const uint4*)(kbase + (size_t)key*ND + hi*8);
  return r.v;
}

__global__ __launch_bounds__(512) void k_attn_fused(
    const u16* __restrict__ q, const u16* __restrict__ k,
    const u16* __restrict__ v, const int* __restrict__ lenbuf,
    const int* __restrict__ order,
    u16* __restrict__ att_t) {
  __shared__ short kv[16384];   // 32 KB: V fragments only
  int bid = blockIdx.x;
  int b  = order[bid >> 5];     // len-DESC schedule (R18 tail fix)
  int h  = (bid >> 2) & 7;
  int qq = bid & 3;
  int tid = threadIdx.x;
  int len = lenbuf[b];
  int nkt = (len + 31) >> 5;
  int kstage = nkt << 5;

  // ---- stage V: (key-pair, d-quad) tasks; interleave two key rows
  for (int idx = tid; idx < 2048; idx += 512) {
    int keyp = idx >> 2, vq = idx & 3;
    int key = keyp*2;
    if (key >= kstage) break;
    int vlo = vq*4;
    uint2 ra, rb; ra.x = ra.y = rb.x = rb.y = 0u;
    size_t voff = ((size_t)b*NL + key)*ND + h*16 + vlo;
    if (key < len)     ra = *(const uint2*)(v + voff);
    if (key + 1 < len) rb = *(const uint2*)(v + voff + ND);
    unsigned wv[4];
    wv[0] = (ra.x & 0xFFFFu) | (rb.x << 16);
    wv[1] = (ra.x >> 16)     | (rb.x & 0xFFFF0000u);
    wv[2] = (ra.y & 0xFFFFu) | (rb.y << 16);
    wv[3] = (ra.y >> 16)     | (rb.y & 0xFFFF0000u);
    int kt = key >> 5, w = key & 31;  // even
    int vhi, ii;
    if (w < 16) { vhi = w >> 2; ii = w & 3; }
    else        { vhi = (w - 16) >> 2; ii = 4 + (w & 3); }
#pragma unroll
    for (int e = 0; e < 4; ++e)
      *(unsigned*)(kv + kt*512 + (vhi*16 + vlo + e)*8 + ii) = wv[e];
  }
  __syncthreads();

  int wave = tid >> 6, lane = tid & 63;
  int lo = lane & 15, hi = lane >> 4;
  int q0 = qq*256 + wave*32;

  bf16x8 qf[2];
#pragma unroll
  for (int qt = 0; qt < 2; ++qt) {
    if (hi < 2) {
      union { uint4 u; bf16x8 v; } qu;
      qu.u = *(const uint4*)(q + ((size_t)b*NL + q0 + qt*16 + lo)*ND + h*16 + hi*8);
      qf[qt] = qu.v;
    } else {
      qf[qt] = (bf16x8){0,0,0,0,0,0,0,0};
    }
  }
  const short oneb = (short)0x3F80;   // bf16 1.0
  bf16x8 onesf = (bf16x8){oneb,oneb,oneb,oneb,oneb,oneb,oneb,oneb};
  f32x4 acc[2], dacc[2];
#pragma unroll
  for (int qt = 0; qt < 2; ++qt) {
    acc[qt]  = (f32x4){0.f,0.f,0.f,0.f};
    dacc[qt] = (f32x4){0.f,0.f,0.f,0.f};
  }

  int fullt = len >> 5;
  const u16* kbase = k + (size_t)b*NL*ND + h*16;

  // register double-buffer: K direct from global (L2), V from LDS
  bf16x8 cka = (bf16x8){0,0,0,0,0,0,0,0}, ckb = cka, cv;
  if (hi < 2) {
    cka = ldKrow(kbase, lo, hi);
    ckb = ldKrow(kbase, 16 + lo, hi);
  }
  cv = *(const bf16x8*)(kv + lane*8);

  for (int kt = 0; kt < nkt; ++kt) {
    bf16x8 nka = cka, nkb = ckb, nv = cv;
    if (kt + 1 < nkt) {
      int kb2 = (kt+1)*32;
      if (hi < 2) {
        nka = ldKrow(kbase, kb2 + lo, hi);
        nkb = ldKrow(kbase, kb2 + 16 + lo, hi);
      }
      nv = *(const bf16x8*)(kv + (kt+1)*512 + lane*8);
    }
    if (kt < fullt) attn_tile<false>(cka, ckb, cv, onesf, qf, acc, dacc, kt*32, len, hi);
    else            attn_tile<true >(cka, ckb, cv, onesf, qf, acc, dacc, kt*32, len, hi);
    cka = nka; ckb = nkb; cv = nv;
  }
#pragma unroll
  for (int qt = 0; qt < 2; ++qt) {
    float inv = 1.f / dacc[qt][0];   // every C-row of ones-MFMA = full row-sum
    size_t obase = ((size_t)b*ND + h*16)*NL + q0 + qt*16 + lo;
#pragma unroll
    for (int r = 0; r < 4; ++r)
      att_t[obase + (size_t)(hi*4 + r)*NL] = bf16rnd(acc[qt][r] * inv);
  }
}

// ---------------- launcher ----------------
extern "C" void kernel_launch(void* const* d_in, const int* in_sizes, int n_in,
                              void* d_out, int out_size, void* d_ws, size_t ws_size,
                              hipStream_t stream) {
  (void)in_sizes; (void)n_in; (void)out_size; (void)ws_size;
  const float* x       = (const float*)d_in[0];
  const float* mask    = (const float*)d_in[1];
  const float* pe      = (const float*)d_in[2];
  const float* normb_w = (const float*)d_in[3];
  const float* normb_b = (const float*)d_in[4];
  const float* dw_w    = (const float*)d_in[5];
  const float* dw_b    = (const float*)d_in[6];
  const float* pw_w    = (const float*)d_in[7];
  const float* pw_b    = (const float*)d_in[8];
  const float* norms_w = (const float*)d_in[9];
  const float* norms_b = (const float*)d_in[10];
  const float* qw      = (const float*)d_in[11];
  const float* qb      = (const float*)d_in[12];
  const float* kw      = (const float*)d_in[13];
  const float* kb      = (const float*)d_in[14];
  const float* vw      = (const float*)d_in[15];
  const float* vb      = (const float*)d_in[16];
  const float* aw      = (const float*)d_in[17];
  const float* ab      = (const float*)d_in[18];
  const float* norme_w = (const float*)d_in[19];
  const float* norme_b = (const float*)d_in[20];
  const float* fw      = (const float*)d_in[21];
  const float* fb      = (const float*)d_in[22];

  float* out = (float*)d_out;
  float* ws  = (float*)d_ws;
  const size_t NT = (size_t)NB*ND*NL;   // element count per (B,D,L) tensor
  u16* resA = (u16*)ws;                  // NT bf16 = NT/2 floats
  u16* resB = (u16*)(ws + NT/2);
  u16* qb16 = (u16*)(ws + NT);
  u16* kb16 = (u16*)(ws + 3*NT/2);
  u16* vb16 = (u16*)(ws + 2*NT);
  float* stats = ws + 3*NT;              // 6 * STATS_R floats
  int* lenbuf = (int*)(stats + 6*STATS_R);
  int* order  = lenbuf + NB;
  u16* att16 = resB;                     // resB free after conv chain

  k_init<<<dim3(NB), dim3(256), 0, stream>>>(mask, stats, lenbuf);
  k_order<<<dim3(1), dim3(NB), 0, stream>>>(lenbuf, order);
  k_addpos<<<dim3(2048), dim3(256), 0, stream>>>(x, pe, resA, stats);

  // conv layers ping-pong A->B->A->B->A (halo reads never race with writes)
  for (int i = 0; i < 4; ++i) {
    const float* lw = (i == 0) ? normb_w : norms_w + (size_t)(i-1)*NDL;
    const float* lb = (i == 0) ? normb_b : norms_b + (size_t)(i-1)*NDL;
    const u16* rsrc = (i & 1) ? resB : resA;
    u16*       rdst = (i & 1) ? resA : resB;
    k_gemm_mfma<0><<<dim3(NB*16), dim3(512), 0, stream>>>(
        rsrc, pw_w + i*ND*ND, pw_b + i*ND, rsrc, rdst, nullptr,
        lw, lb, dw_w + i*ND*7, dw_b + i*ND,
        stats + i*STATS_R, stats + (i+1)*STATS_R);
  }
  // after 4 layers res lives in resA

  const float* ln3w = norms_w + (size_t)3*NDL;
  const float* ln3b = norms_b + (size_t)3*NDL;
  k_qkv_mfma<<<dim3(NB*16), dim3(512), 0, stream>>>(
      resA, qw, kw, vw, qb, kb, vb, qb16, kb16, vb16, ln3w, ln3b, stats + 4*STATS_R);

  k_attn_fused<<<dim3(NB*8*4), dim3(512), 0, stream>>>(qb16, kb16, vb16, lenbuf, order, att16);

  // attn out proj: bf16 src, residual resA, in-place (no halo -> safe)
  k_gemm_mfma<1><<<dim3(NB*16), dim3(512), 0, stream>>>(
      att16, aw, ab, resA, resA, nullptr, nullptr, nullptr, nullptr, nullptr,
      nullptr, stats + 5*STATS_R);
  k_gemm_mfma<3><<<dim3(NB*16), dim3(512), 0, stream>>>(
      resA, fw, fb, resA, nullptr, out, norme_w, norme_b, nullptr, nullptr,
      stats + 5*STATS_R, nullptr);
}

// Round 20
// 166.034 us; speedup vs baseline: 1.2915x; 1.0008x over previous
//
#include <hip/hip_runtime.h>

#define NB 32
#define ND 128
#define NL 1024
#define NDL (ND*NL)   // 131072 per batch
// stats: 6 regions x 32 batches x 16 floats (one 64B cacheline per (r,b))
#define STATS_B 16
#define STATS_R (32*STATS_B)

typedef __attribute__((ext_vector_type(8))) short bf16x8;
typedef __attribute__((ext_vector_type(4))) float f32x4;
typedef unsigned short u16;

__device__ __forceinline__ f32x4 mfma_bf16_16x16x32(bf16x8 a, bf16x8 b, f32x4 c) {
#if defined(__HIP_DEVICE_COMPILE__)
  return __builtin_amdgcn_mfma_f32_16x16x32_bf16(a, b, c, 0, 0, 0);
#else
  return c;
#endif
}

// HW exp2 via BUILTIN (R8 lesson: raw asm hides TRANS hazard -> NaN)
__device__ __forceinline__ float exp2fast(float x) {
#if defined(__HIP_DEVICE_COMPILE__) && __has_builtin(__builtin_amdgcn_exp2f)
  return __builtin_amdgcn_exp2f(x);
#elif defined(__HIP_DEVICE_COMPILE__)
  return __expf(x * 0.6931471805599453f);
#else
  return x;
#endif
}

// bf16 <-> f32 primitives (R7: avoid library cvt NaN-paths; shift is 1 op)
__device__ __forceinline__ float bf2f(u16 u) {
  union { unsigned u; float f; } c; c.u = ((unsigned)u) << 16; return c.f;
}
__device__ __forceinline__ u16 bf16rnd(float f) {
  union { float f; unsigned u; } c; c.f = f;
  return (u16)((c.u + 0x7FFFu + ((c.u >> 16) & 1u)) >> 16);
}
__device__ __forceinline__ unsigned packpair(float a, float b) {
  return (unsigned)bf16rnd(a) | ((unsigned)bf16rnd(b) << 16);
}
// 3-op truncating pack for attention P (R9: trunc bias ~0.2%, headroom allows)
__device__ __forceinline__ unsigned packtrunc(float a, float b) {
  unsigned ua = __float_as_uint(a), ub = __float_as_uint(b);
  return (ub & 0xFFFF0000u) | (ua >> 16);
}
__device__ __forceinline__ bf16x8 packbf8(float4 a, float4 b) {
  union { unsigned u[4]; bf16x8 v; } r;
  r.u[0] = packpair(a.x, a.y); r.u[1] = packpair(a.z, a.w);
  r.u[2] = packpair(b.x, b.y); r.u[3] = packpair(b.z, b.w);
  return r.v;
}

// Block-level sum/sumsq reduction -> ONE atomic pair per block (R4 lesson)
__device__ __forceinline__ void blockRedAtomic(float s, float sq, float* base) {
  __shared__ float red[32];
#pragma unroll
  for (int off = 32; off > 0; off >>= 1) {
    s  += __shfl_down(s, off, 64);
    sq += __shfl_down(sq, off, 64);
  }
  int wave = threadIdx.x >> 6;
  int nw = blockDim.x >> 6;
  if ((threadIdx.x & 63) == 0) { red[wave*2] = s; red[wave*2+1] = sq; }
  __syncthreads();
  if (threadIdx.x == 0) {
    float ts = 0.f, tq = 0.f;
    for (int i = 0; i < nw; ++i) { ts += red[i*2]; tq += red[i*2+1]; }
    unsafeAtomicAdd(base,     ts);
    unsafeAtomicAdd(base + 1, tq);
  }
}

// ---------------- init: block b zeros its stats slice + computes mask len ----
__global__ __launch_bounds__(256) void k_init(const float* __restrict__ mask,
                                              float* __restrict__ stats,
                                              int* __restrict__ lenbuf) {
  __shared__ int csh;
  int b = blockIdx.x, tid = threadIdx.x;
  if (tid == 0) csh = 0;
  for (int i = tid; i < 96; i += 256) stats[b*96 + i] = 0.f;
  __syncthreads();
  int cnt = 0;
  for (int i = tid; i < NL; i += 256) cnt += (mask[(size_t)b*NL + i] == 0.f) ? 1 : 0;
#pragma unroll
  for (int off = 32; off > 0; off >>= 1) cnt += __shfl_down(cnt, off, 64);
  if ((tid & 63) == 0) atomicAdd(&csh, cnt);
  __syncthreads();
  if (tid == 0) lenbuf[b] = csh;
}

// ---------------- rank-sort batches by len DESC -> order[] (R18 tail fix) ----
__global__ void k_order(const int* __restrict__ lenbuf, int* __restrict__ order) {
  int t = threadIdx.x;   // 32 threads
  int mylen = lenbuf[t];
  int rank = 0;
  for (int j = 0; j < NB; ++j) {
    int lj = lenbuf[j];
    rank += (lj > mylen || (lj == mylen && j < t)) ? 1 : 0;
  }
  order[rank] = t;
}

// ---------------- res16 = bf16(x + pos_enc); stats region 0 ----------
__global__ __launch_bounds__(256) void k_addpos(const float* __restrict__ x,
                                                const float* __restrict__ pe,
                                                u16* __restrict__ res,
                                                float* __restrict__ stats0) {
  int b = blockIdx.x >> 6;
  int off = ((blockIdx.x & 63) << 11) + (threadIdx.x << 3);
  const float4* xp = (const float4*)(x + (size_t)b*NDL + off);
  const float4* pp = (const float4*)(pe + off);
  float s = 0.f, sq = 0.f;
  float rv[8];
#pragma unroll
  for (int i = 0; i < 2; ++i) {
    float4 a = xp[i], p = pp[i];
    rv[i*4+0] = a.x + p.x; rv[i*4+1] = a.y + p.y;
    rv[i*4+2] = a.z + p.z; rv[i*4+3] = a.w + p.w;
  }
#pragma unroll
  for (int j = 0; j < 8; ++j) { s += rv[j]; sq += rv[j]*rv[j]; }
  uint4 pk;
  pk.x = packpair(rv[0], rv[1]); pk.y = packpair(rv[2], rv[3]);
  pk.z = packpair(rv[4], rv[5]); pk.w = packpair(rv[6], rv[7]);
  *(uint4*)(res + (size_t)b*NDL + off) = pk;
  blockRedAtomic(s, sq, stats0 + b*STATS_B);
}

// ============ MFMA GEMM — settled config (64-l tiles, 512 thr / 8 waves) ======
// After R11 (split-K lost), R12 (32-l lost), R14/R17 (l-split lost), R15
// (min-waves force spilled): 512 thr, natural VGPR ~60.
// xs layout (u32 = 2 bf16 along c): xs[(l<<6) | (c2 ^ ((l&7)<<2))];
// frag read byte off = (l*256 + kk*64 + hi*16) ^ ((lo&7)<<4) (conflict-free).

__device__ __forceinline__ void load_w_frags16(const float* __restrict__ W,
                                               int wo, int lo, int hi, bf16x8 af[4]) {
#pragma unroll
  for (int kk = 0; kk < 4; ++kk) {
    const float4* wp = (const float4*)(W + (size_t)(wo + lo)*128 + kk*32 + hi*8);
    af[kk] = packbf8(wp[0], wp[1]);
  }
}

__device__ __forceinline__ void mfma_core16(const unsigned* xs, bf16x8 af[4],
                                            int lo, int hi, f32x4 acc[4]) {
#pragma unroll
  for (int ln = 0; ln < 4; ++ln) {
#pragma unroll
    for (int kk = 0; kk < 4; ++kk) {
      int l = ln*16 + lo;
      int off = (l*256 + kk*64 + hi*16) ^ ((lo & 7) << 4);
      bf16x8 bf = *(const bf16x8*)((const char*)xs + off);
      acc[ln] = mfma_bf16_16x16x32(af[kk], bf, acc[ln]);
    }
  }
}

// LN + depthwise-7 conv, bf16 source row, 8 outputs starting at `base`.
__device__ __forceinline__ void conv_row8(const u16* __restrict__ srow,
                                          const float* __restrict__ lwrow,
                                          const float* __restrict__ lbrow,
                                          int base, float mu, float rstd,
                                          const float* wk, float bias0,
                                          float* h /*[8]*/) {
  float wa[14];
  bool interior = (base >= 4) && (base + 12 <= NL);
  if (interior) {
    const uint2* sp = (const uint2*)(srow + base - 4);
    const float4* wp = (const float4*)(lwrow + base - 4);
    const float4* bp = (const float4*)(lbrow + base - 4);
#pragma unroll
    for (int qd = 0; qd < 4; ++qd) {
      uint2 sv2 = sp[qd];
      float4 w4 = wp[qd], b4 = bp[qd];
      float sv[4] = {bf2f((u16)(sv2.x & 0xFFFF)), bf2f((u16)(sv2.x >> 16)),
                     bf2f((u16)(sv2.y & 0xFFFF)), bf2f((u16)(sv2.y >> 16))};
      float wv[4] = {w4.x, w4.y, w4.z, w4.w};
      float bv[4] = {b4.x, b4.y, b4.z, b4.w};
#pragma unroll
      for (int e = 0; e < 4; ++e) {
        int j = qd*4 + e - 1;
        if (j >= 0 && j < 14)
          wa[j] = (sv[e] - mu)*rstd*wv[e] + bv[e];
      }
    }
  } else {
#pragma unroll
    for (int j = 0; j < 14; ++j) {
      int gl = base + j - 3;
      float v = 0.f;
      if (gl >= 0 && gl < NL)
        v = (bf2f(srow[gl]) - mu)*rstd*lwrow[gl] + lbrow[gl];
      wa[j] = v;
    }
  }
#pragma unroll
  for (int l = 0; l < 8; ++l) {
    float acc = bias0;
#pragma unroll
    for (int j = 0; j < 7; ++j) acc += wa[l+j]*wk[j];
    h[l] = acc;
  }
}

// MODE 0: wr16 = bf16(relu(W @ dwconv(LN(src16)) + bias) + res16)  (+stats)
// MODE 1: wr16 = bf16((W@src16 + bias) + res16)                     (+stats)
// MODE 3: outf = relu(W@LN(src16) + bias) + res16                   (f32 out)
template<int MODE>
__global__ __launch_bounds__(512) void k_gemm_mfma(
    const u16* __restrict__ src16, const float* __restrict__ W,
    const float* __restrict__ bias,
    const u16* __restrict__ res16, u16* __restrict__ wr16,
    float* __restrict__ outf,
    const float* __restrict__ lnw, const float* __restrict__ lnb,
    const float* __restrict__ dww, const float* __restrict__ dwb,
    const float* __restrict__ statsIn, float* __restrict__ statsOut) {
  __shared__ unsigned xs[4096];   // 16 KB: 64 l x 128 c bf16
  int b  = blockIdx.x >> 4;
  int l0 = (blockIdx.x & 15) << 6;
  int tid = threadIdx.x;
  int wave = tid >> 6, lane = tid & 63;
  int lo = lane & 15, hi = lane >> 4;
  int wo = wave * 16;

  float mu = 0.f, rstd = 0.f;
  if (MODE == 0 || MODE == 3) {
    mu = statsIn[b*STATS_B] * (1.f/NDL);
    rstd = rsqrtf(statsIn[b*STATS_B + 1]*(1.f/NDL) - mu*mu + 1e-5f);
  }

  if (MODE == 0) {
    int c2 = tid >> 3, lq = tid & 7;
    int c = c2*2, base = l0 + lq*8;
    float wk0[7], wk1[7];
#pragma unroll
    for (int j = 0; j < 7; ++j) { wk0[j] = dww[c*7 + j]; wk1[j] = dww[(c+1)*7 + j]; }
    const u16* sa = src16 + (size_t)b*NDL + (size_t)c*NL;
    const float* la  = lnw + (size_t)c*NL;
    const float* lbv = lnb + (size_t)c*NL;
    float h0[8], h1[8];
    conv_row8(sa,      la,      lbv,      base, mu, rstd, wk0, dwb[c],   h0);
    conv_row8(sa + NL, la + NL, lbv + NL, base, mu, rstd, wk1, dwb[c+1], h1);
#pragma unroll
    for (int l = 0; l < 8; ++l) {
      int ll = lq*8 + l;
      xs[(ll << 6) | (c2 ^ ((ll & 7) << 2))] = packpair(h0[l], h1[l]);
    }
  } else if (MODE == 1) {
    for (int i = tid; i < 1024; i += 512) {
      int c2 = i >> 4, lq = (i & 15) << 2;
      int c = c2*2;
      const u16* sp = src16 + (size_t)b*NDL + (size_t)c*NL + l0 + lq;
      uint2 ra = *(const uint2*)sp;
      uint2 rb = *(const uint2*)(sp + NL);
      unsigned wv[4];
      wv[0] = (ra.x & 0xFFFFu) | (rb.x << 16);
      wv[1] = (ra.x >> 16)     | (rb.x & 0xFFFF0000u);
      wv[2] = (ra.y & 0xFFFFu) | (rb.y << 16);
      wv[3] = (ra.y >> 16)     | (rb.y & 0xFFFF0000u);
#pragma unroll
      for (int j = 0; j < 4; ++j) {
        int l = lq + j;
        xs[(l << 6) | (c2 ^ ((l & 7) << 2))] = wv[j];
      }
    }
  } else {
    for (int i = tid; i < 1024; i += 512) {
      int c2 = i >> 4, lq = (i & 15) << 2;
      int c = c2*2;
      const u16* sp = src16 + (size_t)b*NDL + (size_t)c*NL + l0 + lq;
      uint2 ra = *(const uint2*)sp;
      uint2 rb = *(const uint2*)(sp + NL);
      float sa[4] = {bf2f((u16)(ra.x & 0xFFFF)), bf2f((u16)(ra.x >> 16)),
                     bf2f((u16)(ra.y & 0xFFFF)), bf2f((u16)(ra.y >> 16))};
      float sb[4] = {bf2f((u16)(rb.x & 0xFFFF)), bf2f((u16)(rb.x >> 16)),
                     bf2f((u16)(rb.y & 0xFFFF)), bf2f((u16)(rb.y >> 16))};
      size_t gi = (size_t)c*NL + l0 + lq;
      float4 w0 = *(const float4*)(lnw + gi), w1 = *(const float4*)(lnw + gi + NL);
      float4 bb0 = *(const float4*)(lnb + gi), bb1 = *(const float4*)(lnb + gi + NL);
      float va[4] = {(sa[0]-mu)*rstd*w0.x + bb0.x, (sa[1]-mu)*rstd*w0.y + bb0.y,
                     (sa[2]-mu)*rstd*w0.z + bb0.z, (sa[3]-mu)*rstd*w0.w + bb0.w};
      float vb[4] = {(sb[0]-mu)*rstd*w1.x + bb1.x, (sb[1]-mu)*rstd*w1.y + bb1.y,
                     (sb[2]-mu)*rstd*w1.z + bb1.z, (sb[3]-mu)*rstd*w1.w + bb1.w};
#pragma unroll
      for (int j = 0; j < 4; ++j) {
        int l = lq + j;
        xs[(l << 6) | (c2 ^ ((l & 7) << 2))] = packpair(va[j], vb[j]);
      }
    }
  }

  // prefetch residual (R13: hide epilogue HBM latency under staging+MFMA)
  u16 rpre[16];
#pragma unroll
  for (int ln = 0; ln < 4; ++ln)
#pragma unroll
    for (int r = 0; r < 4; ++r)
      rpre[ln*4+r] = res16[((size_t)b*ND + wo + hi*4 + r)*NL + l0 + ln*16 + lo];

  bf16x8 af[4];
  load_w_frags16(W, wo, lo, hi, af);
  f32x4 acc[4];
#pragma unroll
  for (int ln = 0; ln < 4; ++ln) acc[ln] = (f32x4){0.f,0.f,0.f,0.f};

  __syncthreads();
  mfma_core16(xs, af, lo, hi, acc);

  if (MODE == 0 || MODE == 1) {
    float s = 0.f, sq = 0.f;
#pragma unroll
    for (int ln = 0; ln < 4; ++ln) {
      int l = l0 + ln*16 + lo;
#pragma unroll
      for (int r = 0; r < 4; ++r) {
        int o = wo + hi*4 + r;
        size_t gi = ((size_t)b*ND + o)*NL + l;
        float v = acc[ln][r] + bias[o];
        if (MODE == 0) v = fmaxf(v, 0.f);
        v += bf2f(rpre[ln*4+r]);
        wr16[gi] = bf16rnd(v);
        s += v; sq += v*v;
      }
    }
    blockRedAtomic(s, sq, statsOut + b*STATS_B);
  } else {
#pragma unroll
    for (int ln = 0; ln < 4; ++ln) {
      int l = l0 + ln*16 + lo;
#pragma unroll
      for (int r = 0; r < 4; ++r) {
        int o = wo + hi*4 + r;
        size_t gi = ((size_t)b*ND + o)*NL + l;
        outf[gi] = fmaxf(acc[ln][r] + bias[o], 0.f) + bf2f(rpre[ln*4+r]);
      }
    }
  }
}

// Fused QKV (settled config + R19 len-skip): stage LN(bf16 src) once, 3 GEMMs.
// K/V tiles with l0 >= ceil(len/32)*32 are never read by attention -> skipped
// (block-uniform branch; stale data in skipped rows is unread or select-zeroed).
// q scaled by 0.25*log2e so attention uses raw HW exp2.
__global__ __launch_bounds__(512) void k_qkv_mfma(
    const u16* __restrict__ src16,
    const float* __restrict__ qw, const float* __restrict__ kw, const float* __restrict__ vw,
    const float* __restrict__ qb, const float* __restrict__ kb, const float* __restrict__ vb,
    u16* __restrict__ qo, u16* __restrict__ ko, u16* __restrict__ vo,
    const float* __restrict__ lnw, const float* __restrict__ lnb,
    const float* __restrict__ statsIn, const int* __restrict__ lenbuf) {
  __shared__ unsigned xs[4096];
  int b  = blockIdx.x >> 4;
  int l0 = (blockIdx.x & 15) << 6;
  int tid = threadIdx.x;
  int wave = tid >> 6, lane = tid & 63;
  int lo = lane & 15, hi = lane >> 4;
  int wo = wave * 16;
  int kneed = ((lenbuf[b] + 31) >> 5) << 5;   // keys actually consumed by attn

  float mu = statsIn[b*STATS_B] * (1.f/NDL);
  float rstd = rsqrtf(statsIn[b*STATS_B + 1]*(1.f/NDL) - mu*mu + 1e-5f);
  for (int i = tid; i < 1024; i += 512) {
    int c2 = i >> 4, lq = (i & 15) << 2;
    int c = c2*2;
    const u16* sp = src16 + (size_t)b*NDL + (size_t)c*NL + l0 + lq;
    uint2 ra = *(const uint2*)sp;
    uint2 rb = *(const uint2*)(sp + NL);
    float sa[4] = {bf2f((u16)(ra.x & 0xFFFF)), bf2f((u16)(ra.x >> 16)),
                   bf2f((u16)(ra.y & 0xFFFF)), bf2f((u16)(ra.y >> 16))};
    float sb[4] = {bf2f((u16)(rb.x & 0xFFFF)), bf2f((u16)(rb.x >> 16)),
                   bf2f((u16)(rb.y & 0xFFFF)), bf2f((u16)(rb.y >> 16))};
    size_t gi = (size_t)c*NL + l0 + lq;
    float4 w0 = *(const float4*)(lnw + gi), w1 = *(const float4*)(lnw + gi + NL);
    float4 bb0 = *(const float4*)(lnb + gi), bb1 = *(const float4*)(lnb + gi + NL);
    float va[4] = {(sa[0]-mu)*rstd*w0.x + bb0.x, (sa[1]-mu)*rstd*w0.y + bb0.y,
                   (sa[2]-mu)*rstd*w0.z + bb0.z, (sa[3]-mu)*rstd*w0.w + bb0.w};
    float vb4[4] = {(sb[0]-mu)*rstd*w1.x + bb1.x, (sb[1]-mu)*rstd*w1.y + bb1.y,
                    (sb[2]-mu)*rstd*w1.z + bb1.z, (sb[3]-mu)*rstd*w1.w + bb1.w};
#pragma unroll
    for (int j = 0; j < 4; ++j) {
      int l = lq + j;
      xs[(l << 6) | (c2 ^ ((l & 7) << 2))] = packpair(va[j], vb4[j]);
    }
  }
  __syncthreads();

  const float* Ws[3] = {qw, kw, vw};
  const float* Bs[3] = {qb, kb, vb};
  u16* Os[3] = {qo, ko, vo};
#pragma unroll 1
  for (int mat = 0; mat < 3; ++mat) {
    if (mat > 0 && l0 >= kneed) continue;   // K/V rows never read by attn
    bf16x8 af[4];
    load_w_frags16(Ws[mat], wo, lo, hi, af);
    f32x4 acc[4];
#pragma unroll
    for (int ln = 0; ln < 4; ++ln) acc[ln] = (f32x4){0.f,0.f,0.f,0.f};
    mfma_core16(xs, af, lo, hi, acc);
    float oscale = (mat == 0) ? 0.25f*1.4426950408889634f : 1.0f;
    const float* bias = Bs[mat];
    u16* op = Os[mat];
#pragma unroll
    for (int ln = 0; ln < 4; ++ln) {
      int l = l0 + ln*16 + lo;
      int o4 = wo + hi*4;
      float vx = (acc[ln][0] + bias[o4+0]) * oscale;
      float vy = (acc[ln][1] + bias[o4+1]) * oscale;
      float vz = (acc[ln][2] + bias[o4+2]) * oscale;
      float vw4 = (acc[ln][3] + bias[o4+3]) * oscale;
      uint2 pk; pk.x = packpair(vx, vy); pk.y = packpair(vz, vw4);
      *(uint2*)(op + ((size_t)b*NL + l)*ND + o4) = pk;
    }
  }
}

// ---------------- fused MFMA attention (quarter-split, V-only LDS) ------------
// R16 config + R18 len-DESC schedule.
template<bool MASKED>
__device__ __forceinline__ void attn_tile(bf16x8 kf0, bf16x8 kf1, bf16x8 vf,
                                          bf16x8 onesf, const bf16x8 qf[2],
                                          f32x4 acc[2], f32x4 dacc[2],
                                          int kb, int len, int hi) {
#pragma unroll
  for (int qt = 0; qt < 2; ++qt) {
    f32x4 z = (f32x4){0.f,0.f,0.f,0.f};
    f32x4 s0 = mfma_bf16_16x16x32(kf0, qf[qt], z);
    f32x4 s1 = mfma_bf16_16x16x32(kf1, qf[qt], z);
    float e[8];
#pragma unroll
    for (int r = 0; r < 4; ++r) {
      float e0 = exp2fast(s0[r]);
      float e1 = exp2fast(s1[r]);
      if (MASKED) {
        e0 = (kb + hi*4 + r < len)      ? e0 : 0.f;
        e1 = (kb + 16 + hi*4 + r < len) ? e1 : 0.f;
      }
      e[r] = e0; e[r+4] = e1;
    }
    union { unsigned u[4]; bf16x8 v; } pu;
    pu.u[0] = packtrunc(e[0], e[1]);
    pu.u[1] = packtrunc(e[2], e[3]);
    pu.u[2] = packtrunc(e[4], e[5]);
    pu.u[3] = packtrunc(e[6], e[7]);
    acc[qt]  = mfma_bf16_16x16x32(vf,    pu.v, acc[qt]);
    dacc[qt] = mfma_bf16_16x16x32(onesf, pu.v, dacc[qt]);
  }
}

__device__ __forceinline__ bf16x8 ldKrow(const u16* kbase, int key, int hi) {
  union { uint4 u; bf16x8 v; } r;
  r.u = *(const uint4*)(kbase + (size_t)key*ND + hi*8);
  return r.v;
}

__global__ __launch_bounds__(512) void k_attn_fused(
    const u16* __restrict__ q, const u16* __restrict__ k,
    const u16* __restrict__ v, const int* __restrict__ lenbuf,
    const int* __restrict__ order,
    u16* __restrict__ att_t) {
  __shared__ short kv[16384];   // 32 KB: V fragments only
  int bid = blockIdx.x;
  int b  = order[bid >> 5];     // len-DESC schedule (R18 tail fix)
  int h  = (bid >> 2) & 7;
  int qq = bid & 3;
  int tid = threadIdx.x;
  int len = lenbuf[b];
  int nkt = (len + 31) >> 5;
  int kstage = nkt << 5;

  // ---- stage V: (key-pair, d-quad) tasks; interleave two key rows
  for (int idx = tid; idx < 2048; idx += 512) {
    int keyp = idx >> 2, vq = idx & 3;
    int key = keyp*2;
    if (key >= kstage) break;
    int vlo = vq*4;
    uint2 ra, rb; ra.x = ra.y = rb.x = rb.y = 0u;
    size_t voff = ((size_t)b*NL + key)*ND + h*16 + vlo;
    if (key < len)     ra = *(const uint2*)(v + voff);
    if (key + 1 < len) rb = *(const uint2*)(v + voff + ND);
    unsigned wv[4];
    wv[0] = (ra.x & 0xFFFFu) | (rb.x << 16);
    wv[1] = (ra.x >> 16)     | (rb.x & 0xFFFF0000u);
    wv[2] = (ra.y & 0xFFFFu) | (rb.y << 16);
    wv[3] = (ra.y >> 16)     | (rb.y & 0xFFFF0000u);
    int kt = key >> 5, w = key & 31;  // even
    int vhi, ii;
    if (w < 16) { vhi = w >> 2; ii = w & 3; }
    else        { vhi = (w - 16) >> 2; ii = 4 + (w & 3); }
#pragma unroll
    for (int e = 0; e < 4; ++e)
      *(unsigned*)(kv + kt*512 + (vhi*16 + vlo + e)*8 + ii) = wv[e];
  }
  __syncthreads();

  int wave = tid >> 6, lane = tid & 63;
  int lo = lane & 15, hi = lane >> 4;
  int q0 = qq*256 + wave*32;

  bf16x8 qf[2];
#pragma unroll
  for (int qt = 0; qt < 2; ++qt) {
    if (hi < 2) {
      union { uint4 u; bf16x8 v; } qu;
      qu.u = *(const uint4*)(q + ((size_t)b*NL + q0 + qt*16 + lo)*ND + h*16 + hi*8);
      qf[qt] = qu.v;
    } else {
      qf[qt] = (bf16x8){0,0,0,0,0,0,0,0};
    }
  }
  const short oneb = (short)0x3F80;   // bf16 1.0
  bf16x8 onesf = (bf16x8){oneb,oneb,oneb,oneb,oneb,oneb,oneb,oneb};
  f32x4 acc[2], dacc[2];
#pragma unroll
  for (int qt = 0; qt < 2; ++qt) {
    acc[qt]  = (f32x4){0.f,0.f,0.f,0.f};
    dacc[qt] = (f32x4){0.f,0.f,0.f,0.f};
  }

  int fullt = len >> 5;
  const u16* kbase = k + (size_t)b*NL*ND + h*16;

  // register double-buffer: K direct from global (L2), V from LDS
  bf16x8 cka = (bf16x8){0,0,0,0,0,0,0,0}, ckb = cka, cv;
  if (hi < 2) {
    cka = ldKrow(kbase, lo, hi);
    ckb = ldKrow(kbase, 16 + lo, hi);
  }
  cv = *(const bf16x8*)(kv + lane*8);

  for (int kt = 0; kt < nkt; ++kt) {
    bf16x8 nka = cka, nkb = ckb, nv = cv;
    if (kt + 1 < nkt) {
      int kb2 = (kt+1)*32;
      if (hi < 2) {
        nka = ldKrow(kbase, kb2 + lo, hi);
        nkb = ldKrow(kbase, kb2 + 16 + lo, hi);
      }
      nv = *(const bf16x8*)(kv + (kt+1)*512 + lane*8);
    }
    if (kt < fullt) attn_tile<false>(cka, ckb, cv, onesf, qf, acc, dacc, kt*32, len, hi);
    else            attn_tile<true >(cka, ckb, cv, onesf, qf, acc, dacc, kt*32, len, hi);
    cka = nka; ckb = nkb; cv = nv;
  }
#pragma unroll
  for (int qt = 0; qt < 2; ++qt) {
    float inv = 1.f / dacc[qt][0];   // every C-row of ones-MFMA = full row-sum
    size_t obase = ((size_t)b*ND + h*16)*NL + q0 + qt*16 + lo;
#pragma unroll
    for (int r = 0; r < 4; ++r)
      att_t[obase + (size_t)(hi*4 + r)*NL] = bf16rnd(acc[qt][r] * inv);
  }
}

// ---------------- launcher ----------------
extern "C" void kernel_launch(void* const* d_in, const int* in_sizes, int n_in,
                              void* d_out, int out_size, void* d_ws, size_t ws_size,
                              hipStream_t stream) {
  (void)in_sizes; (void)n_in; (void)out_size; (void)ws_size;
  const float* x       = (const float*)d_in[0];
  const float* mask    = (const float*)d_in[1];
  const float* pe      = (const float*)d_in[2];
  const float* normb_w = (const float*)d_in[3];
  const float* normb_b = (const float*)d_in[4];
  const float* dw_w    = (const float*)d_in[5];
  const float* dw_b    = (const float*)d_in[6];
  const float* pw_w    = (const float*)d_in[7];
  const float* pw_b    = (const float*)d_in[8];
  const float* norms_w = (const float*)d_in[9];
  const float* norms_b = (const float*)d_in[10];
  const float* qw      = (const float*)d_in[11];
  const float* qb      = (const float*)d_in[12];
  const float* kw      = (const float*)d_in[13];
  const float* kb      = (const float*)d_in[14];
  const float* vw      = (const float*)d_in[15];
  const float* vb      = (const float*)d_in[16];
  const float* aw      = (const float*)d_in[17];
  const float* ab      = (const float*)d_in[18];
  const float* norme_w = (const float*)d_in[19];
  const float* norme_b = (const float*)d_in[20];
  const float* fw      = (const float*)d_in[21];
  const float* fb      = (const float*)d_in[22];

  float* out = (float*)d_out;
  float* ws  = (float*)d_ws;
  const size_t NT = (size_t)NB*ND*NL;   // element count per (B,D,L) tensor
  u16* resA = (u16*)ws;                  // NT bf16 = NT/2 floats
  u16* resB = (u16*)(ws + NT/2);
  u16* qb16 = (u16*)(ws + NT);
  u16* kb16 = (u16*)(ws + 3*NT/2);
  u16* vb16 = (u16*)(ws + 2*NT);
  float* stats = ws + 3*NT;              // 6 * STATS_R floats
  int* lenbuf = (int*)(stats + 6*STATS_R);
  int* order  = lenbuf + NB;
  u16* att16 = resB;                     // resB free after conv chain

  k_init<<<dim3(NB), dim3(256), 0, stream>>>(mask, stats, lenbuf);
  k_order<<<dim3(1), dim3(NB), 0, stream>>>(lenbuf, order);
  k_addpos<<<dim3(2048), dim3(256), 0, stream>>>(x, pe, resA, stats);

  // conv layers ping-pong A->B->A->B->A (halo reads never race with writes)
  for (int i = 0; i < 4; ++i) {
    const float* lw = (i == 0) ? normb_w : norms_w + (size_t)(i-1)*NDL;
    const float* lb = (i == 0) ? normb_b : norms_b + (size_t)(i-1)*NDL;
    const u16* rsrc = (i & 1) ? resB : resA;
    u16*       rdst = (i & 1) ? resA : resB;
    k_gemm_mfma<0><<<dim3(NB*16), dim3(512), 0, stream>>>(
        rsrc, pw_w + i*ND*ND, pw_b + i*ND, rsrc, rdst, nullptr,
        lw, lb, dw_w + i*ND*7, dw_b + i*ND,
        stats + i*STATS_R, stats + (i+1)*STATS_R);
  }
  // after 4 layers res lives in resA

  const float* ln3w = norms_w + (size_t)3*NDL;
  const float* ln3b = norms_b + (size_t)3*NDL;
  k_qkv_mfma<<<dim3(NB*16), dim3(512), 0, stream>>>(
      resA, qw, kw, vw, qb, kb, vb, qb16, kb16, vb16, ln3w, ln3b,
      stats + 4*STATS_R, lenbuf);

  k_attn_fused<<<dim3(NB*8*4), dim3(512), 0, stream>>>(qb16, kb16, vb16, lenbuf, order, att16);

  // attn out proj: bf16 src, residual resA, in-place (no halo -> safe)
  k_gemm_mfma<1><<<dim3(NB*16), dim3(512), 0, stream>>>(
      att16, aw, ab, resA, resA, nullptr, nullptr, nullptr, nullptr, nullptr,
      nullptr, stats + 5*STATS_R);
  k_gemm_mfma<3><<<dim3(NB*16), dim3(512), 0, stream>>>(
      resA, fw, fb, resA, nullptr, out, norme_w, norme_b, nullptr, nullptr,
      stats + 5*STATS_R, nullptr);
}